// Round 1
// baseline (1016.260 us; speedup 1.0000x reference)
//
#include <hip/hip_runtime.h>
#include <math.h>

#define NB 8
#define NS 2048
#define NDIM 4
#define NH 64
#define NL 3
#define NN (NB*NS)       // 16384 nodes
#define NE (NN*16)       // 262144 edges
#define EPSF 1e-5f

__device__ __forceinline__ float rl(float v, int i) {
    return __int_as_float(__builtin_amdgcn_readlane(__float_as_int(v), i));
}

// Two-layer MLP on concat(xi, xj): out = relu(W2^T relu(W1^T [xi;xj] + b1) + b2)
// lane = output channel (0..63); Q independent rows per wave; weights in LDS
// in original [K][64] layout -> stride-1 conflict-free LDS reads shared by all Q.
template<int Q>
__device__ __forceinline__ void mlp2(const float* __restrict__ sW1,
                                     const float* __restrict__ sW2,
                                     float b1v, float b2v, int lane,
                                     const float* xi, const float* xj,
                                     float* outv)
{
    float a[Q];
    #pragma unroll
    for (int q = 0; q < Q; q++) a[q] = b1v;
    #pragma unroll 4
    for (int i = 0; i < 64; i++) {
        float w = sW1[i*64 + lane];
        #pragma unroll
        for (int q = 0; q < Q; q++) a[q] = fmaf(w, rl(xi[q], i), a[q]);
    }
    #pragma unroll 4
    for (int i = 0; i < 64; i++) {
        float w = sW1[(64+i)*64 + lane];
        #pragma unroll
        for (int q = 0; q < Q; q++) a[q] = fmaf(w, rl(xj[q], i), a[q]);
    }
    #pragma unroll
    for (int q = 0; q < Q; q++) a[q] = fmaxf(a[q], 0.f);
    float c[Q];
    #pragma unroll
    for (int q = 0; q < Q; q++) c[q] = b2v;
    #pragma unroll 4
    for (int i = 0; i < 64; i++) {
        float w = sW2[i*64 + lane];
        #pragma unroll
        for (int q = 0; q < Q; q++) c[q] = fmaf(w, rl(a[q], i), c[q]);
    }
    #pragma unroll
    for (int q = 0; q < Q; q++) outv[q] = fmaxf(c[q], 0.f);
}

__global__ void k_zero(float* __restrict__ p, int n) {
    int i = blockIdx.x * 256 + threadIdx.x;
    if (i < n) p[i] = 0.f;
}

// h = x @ enc_w + enc_b   (no activation)
__global__ __launch_bounds__(256) void k_enc(const float* __restrict__ x,
                                             const float* __restrict__ W,
                                             const float* __restrict__ b,
                                             float* __restrict__ h)
{
    int idx = blockIdx.x * 256 + threadIdx.x;   // over NN*64
    int j = idx & 63, n = idx >> 6;
    const float4 xr = *(const float4*)&x[n*4];
    float a = b[j];
    a = fmaf(xr.x, W[0*64+j], a);
    a = fmaf(xr.y, W[1*64+j], a);
    a = fmaf(xr.z, W[2*64+j], a);
    a = fmaf(xr.w, W[3*64+j], a);
    h[idx] = a;
}

// per-edge message MLP + scatter-add into agg[tgt]
__global__ __launch_bounds__(256) void k_edge(
    const float* __restrict__ h, const int* __restrict__ src, const int* __restrict__ tgt,
    const float* __restrict__ W1, const float* __restrict__ B1,
    const float* __restrict__ W2, const float* __restrict__ B2,
    float* __restrict__ agg)
{
    __shared__ float sW1[128*64];
    __shared__ float sW2[64*64];
    for (int idx = threadIdx.x; idx < 128*64; idx += 256) sW1[idx] = W1[idx];
    for (int idx = threadIdx.x; idx < 64*64; idx += 256)  sW2[idx] = W2[idx];
    __syncthreads();
    const int lane = threadIdx.x & 63;
    const int wid  = blockIdx.x*4 + (threadIdx.x >> 6);
    const int stride = gridDim.x * 4 * 8;
    const float b1v = B1[lane], b2v = B2[lane];
    for (int e0 = wid*8; e0 < NE; e0 += stride) {
        int tg[8], sr[8];
        float xi[8], xj[8], ov[8];
        #pragma unroll
        for (int q = 0; q < 8; q++) { tg[q] = tgt[e0+q]; sr[q] = src[e0+q]; }
        #pragma unroll
        for (int q = 0; q < 8; q++) {
            xi[q] = h[tg[q]*64 + lane];   // x_i = h[tgt]
            xj[q] = h[sr[q]*64 + lane];   // x_j = h[src]
        }
        mlp2<8>(sW1, sW2, b1v, b2v, lane, xi, xj, ov);
        #pragma unroll
        for (int q = 0; q < 8; q++) atomicAdd(&agg[tg[q]*64 + lane], ov[q]);
    }
}

// node update MLP on concat(h, agg), in-place into h
__global__ __launch_bounds__(256) void k_update(
    float* __restrict__ h, const float* __restrict__ agg,
    const float* __restrict__ W1, const float* __restrict__ B1,
    const float* __restrict__ W2, const float* __restrict__ B2)
{
    __shared__ float sW1[128*64];
    __shared__ float sW2[64*64];
    for (int idx = threadIdx.x; idx < 128*64; idx += 256) sW1[idx] = W1[idx];
    for (int idx = threadIdx.x; idx < 64*64; idx += 256)  sW2[idx] = W2[idx];
    __syncthreads();
    const int lane = threadIdx.x & 63;
    const int wid  = blockIdx.x*4 + (threadIdx.x >> 6);
    const int stride = gridDim.x * 4 * 8;
    const float b1v = B1[lane], b2v = B2[lane];
    for (int n0 = wid*8; n0 < NN; n0 += stride) {
        float xi[8], xj[8], ov[8];
        #pragma unroll
        for (int q = 0; q < 8; q++) {
            xi[q] = h[(n0+q)*64 + lane];
            xj[q] = agg[(n0+q)*64 + lane];
        }
        mlp2<8>(sW1, sW2, b1v, b2v, lane, xi, xj, ov);
        #pragma unroll
        for (int q = 0; q < 8; q++) h[(n0+q)*64 + lane] = ov[q];
    }
}

// per-(graph,chunk) partial sums for instance-norm stats
__global__ __launch_bounds__(256) void k_stats(const float* __restrict__ h,
                                               float* __restrict__ gsum,
                                               float* __restrict__ gsq)
{
    int b = blockIdx.x >> 3, c = blockIdx.x & 7;   // 8 graphs x 8 chunks
    int j = threadIdx.x & 63, r = threadIdx.x >> 6;
    int base = b*NS + c*256;
    float s = 0.f, q = 0.f;
    for (int i = r; i < 256; i += 4) {
        float v = h[(base+i)*64 + j];
        s += v; q += v*v;
    }
    __shared__ float ls[4][64], lq[4][64];
    ls[r][j] = s; lq[r][j] = q;
    __syncthreads();
    if (r == 0) {
        s = ls[0][j]+ls[1][j]+ls[2][j]+ls[3][j];
        q = lq[0][j]+lq[1][j]+lq[2][j]+lq[3][j];
        atomicAdd(&gsum[b*64+j], s);
        atomicAdd(&gsq[b*64+j], q);
    }
}

__global__ __launch_bounds__(256) void k_norm(float* __restrict__ h,
                                              const float* __restrict__ gsum,
                                              const float* __restrict__ gsq)
{
    int idx = blockIdx.x * 256 + threadIdx.x;   // over NN*64
    int j = idx & 63; int n = idx >> 6; int b = n >> 11;
    float mean = gsum[b*64+j] * (1.f/NS);
    float var  = gsq[b*64+j] * (1.f/NS) - mean*mean;
    h[idx] = (h[idx] - mean) * rsqrtf(var + EPSF);
}

// X = sigmoid(h @ dec_w + dec_b); write aligned copy (xbuf) + d_out (+1 offset)
__global__ __launch_bounds__(256) void k_dec(const float* __restrict__ h,
                                             const float* __restrict__ Wd,
                                             const float* __restrict__ bd,
                                             float* __restrict__ xbuf,
                                             float* __restrict__ out1)
{
    int n = blockIdx.x * 256 + threadIdx.x;   // NN threads
    float acc0 = bd[0], acc1 = bd[1], acc2 = bd[2], acc3 = bd[3];
    const float* hr = h + n*64;
    #pragma unroll
    for (int j4 = 0; j4 < 64; j4 += 4) {
        float4 v = *(const float4*)&hr[j4];
        acc0 = fmaf(v.x, Wd[(j4+0)*4+0], acc0); acc1 = fmaf(v.x, Wd[(j4+0)*4+1], acc1);
        acc2 = fmaf(v.x, Wd[(j4+0)*4+2], acc2); acc3 = fmaf(v.x, Wd[(j4+0)*4+3], acc3);
        acc0 = fmaf(v.y, Wd[(j4+1)*4+0], acc0); acc1 = fmaf(v.y, Wd[(j4+1)*4+1], acc1);
        acc2 = fmaf(v.y, Wd[(j4+1)*4+2], acc2); acc3 = fmaf(v.y, Wd[(j4+1)*4+3], acc3);
        acc0 = fmaf(v.z, Wd[(j4+2)*4+0], acc0); acc1 = fmaf(v.z, Wd[(j4+2)*4+1], acc1);
        acc2 = fmaf(v.z, Wd[(j4+2)*4+2], acc2); acc3 = fmaf(v.z, Wd[(j4+2)*4+3], acc3);
        acc0 = fmaf(v.w, Wd[(j4+3)*4+0], acc0); acc1 = fmaf(v.w, Wd[(j4+3)*4+1], acc1);
        acc2 = fmaf(v.w, Wd[(j4+3)*4+2], acc2); acc3 = fmaf(v.w, Wd[(j4+3)*4+3], acc3);
    }
    float4 o;
    o.x = 1.f/(1.f + expf(-acc0));
    o.y = 1.f/(1.f + expf(-acc1));
    o.z = 1.f/(1.f + expf(-acc2));
    o.w = 1.f/(1.f + expf(-acc3));
    *(float4*)&xbuf[n*4] = o;
    out1[n*4+0] = o.x; out1[n*4+1] = o.y; out1[n*4+2] = o.z; out1[n*4+3] = o.w;
}

// A2 = sum over all nodes of prod_k (1 - x_k^2)
__global__ __launch_bounds__(256) void k_t2(const float* __restrict__ X,
                                            float* __restrict__ accum)
{
    int n = blockIdx.x * 256 + threadIdx.x;
    float4 x = *(const float4*)&X[n*4];
    float p = (1.f-x.x*x.x)*(1.f-x.y*x.y)*(1.f-x.z*x.z)*(1.f-x.w*x.w);
    for (int off = 32; off; off >>= 1) p += __shfl_down(p, off, 64);
    __shared__ float ws[4];
    if ((threadIdx.x & 63) == 0) ws[threadIdx.x >> 6] = p;
    __syncthreads();
    if (threadIdx.x == 0) atomicAdd(&accum[0], ws[0]+ws[1]+ws[2]+ws[3]);
}

// A3 = sum over graphs of sum_{i,j} prod_k (1 - max(x_ik, x_jk))
__global__ __launch_bounds__(256) void k_t3(const float* __restrict__ X,
                                            float* __restrict__ accum)
{
    int b = blockIdx.x >> 5, c = blockIdx.x & 31;   // 8 graphs x 32 i-chunks of 64
    __shared__ float sX[NS*4];
    const float* Xb = X + b*NS*4;
    for (int idx = threadIdx.x; idx < NS*4; idx += 256) sX[idx] = Xb[idx];
    __syncthreads();
    const float4* sX4 = (const float4*)sX;
    int il = threadIdx.x & 63, wv = threadIdx.x >> 6;  // wave wv owns j-quarter wv (uniform per wave -> LDS broadcast)
    float4 xi = sX4[c*64 + il];
    float acc = 0.f;
    #pragma unroll 4
    for (int s = 0; s < 512; s++) {
        float4 xj = sX4[wv*512 + s];
        float t = (1.f - fmaxf(xi.x, xj.x)) * (1.f - fmaxf(xi.y, xj.y))
                * (1.f - fmaxf(xi.z, xj.z)) * (1.f - fmaxf(xi.w, xj.w));
        acc += t;
    }
    for (int off = 32; off; off >>= 1) acc += __shfl_down(acc, off, 64);
    __shared__ float ws[4];
    if ((threadIdx.x & 63) == 0) ws[threadIdx.x >> 6] = acc;
    __syncthreads();
    if (threadIdx.x == 0) atomicAdd(&accum[1], ws[0]+ws[1]+ws[2]+ws[3]);
}

__global__ void k_fin(const float* __restrict__ accum, float* __restrict__ out)
{
    if (threadIdx.x == 0 && blockIdx.x == 0) {
        float A2 = accum[0], A3 = accum[1];
        float t1 = 1.f/81.f;                              // (1/3)^4
        float t2 = (2.f/(NS*16.f)) * (A2 / NB);           // mean over graphs
        float t3 = (A3 / ((float)NS*(float)NS)) / NB;
        out[0] = t1 - t2 + t3;
    }
}

extern "C" void kernel_launch(void* const* d_in, const int* in_sizes, int n_in,
                              void* d_out, int out_size, void* d_ws, size_t ws_size,
                              hipStream_t stream)
{
    const float* x     = (const float*)d_in[0];
    const int*   ei    = (const int*)d_in[1];
    const float* enc_w = (const float*)d_in[2];
    const float* enc_b = (const float*)d_in[3];
    const float* m1w   = (const float*)d_in[4];
    const float* m1b   = (const float*)d_in[5];
    const float* m2w   = (const float*)d_in[6];
    const float* m2b   = (const float*)d_in[7];
    const float* u1w   = (const float*)d_in[8];
    const float* u1b   = (const float*)d_in[9];
    const float* u2w   = (const float*)d_in[10];
    const float* u2b   = (const float*)d_in[11];
    const float* dw    = (const float*)d_in[12];
    const float* db    = (const float*)d_in[13];
    float* out = (float*)d_out;

    float* h    = (float*)d_ws;            // NN*64
    float* agg  = h    + NN*64;            // NN*64
    float* xbuf = agg  + NN*64;            // NN*4 (16B-aligned copy of X)
    float* gsum = xbuf + NN*4;             // NB*64
    float* gsq  = gsum + NB*64;            // NB*64
    float* acc  = gsq  + NB*64;            // 2

    const int* srcv = ei;        // edge_index[0]
    const int* tgtv = ei + NE;   // edge_index[1]

    k_enc<<<NN*64/256, 256, 0, stream>>>(x, enc_w, enc_b, h);

    for (int l = 0; l < NL; l++) {
        k_zero<<<(NN*64 + 255)/256, 256, 0, stream>>>(agg, NN*64);
        k_edge<<<1024, 256, 0, stream>>>(h, srcv, tgtv,
                                         m1w + l*128*64, m1b + l*64,
                                         m2w + l*64*64,  m2b + l*64, agg);
        k_update<<<256, 256, 0, stream>>>(h, agg,
                                          u1w + l*128*64, u1b + l*64,
                                          u2w + l*64*64,  u2b + l*64);
        k_zero<<<(NB*64*2 + 2 + 255)/256, 256, 0, stream>>>(gsum, NB*64*2 + 2);
        k_stats<<<NB*8, 256, 0, stream>>>(h, gsum, gsq);
        k_norm<<<NN*64/256, 256, 0, stream>>>(h, gsum, gsq);
    }

    k_dec<<<NN/256, 256, 0, stream>>>(h, dw, db, xbuf, out + 1);
    k_t2<<<NN/256, 256, 0, stream>>>(xbuf, acc);
    k_t3<<<NB*32, 256, 0, stream>>>(xbuf, acc);
    k_fin<<<1, 64, 0, stream>>>(acc, out);
}

// Round 2
// 549.000 us; speedup vs baseline: 1.8511x; 1.8511x over previous
//
#include <hip/hip_runtime.h>
#include <math.h>

#define NB 8
#define NS 2048
#define NDIM 4
#define NH 64
#define NL 3
#define NN (NB*NS)       // 16384 nodes
#define NE (NN*16)       // 262144 edges
#define EPSF 1e-5f

__device__ __forceinline__ float rl(float v, int i) {
    return __int_as_float(__builtin_amdgcn_readlane(__float_as_int(v), i));
}

// Two-layer MLP on concat(xi, xj): out = relu(W2^T relu(W1^T [xi;xj] + b1) + b2)
// lane = output channel; Q rows per wave; weights in LDS [K][64] -> stride-1.
template<int Q>
__device__ __forceinline__ void mlp2(const float* __restrict__ sW1,
                                     const float* __restrict__ sW2,
                                     float b1v, float b2v, int lane,
                                     const float* xi, const float* xj,
                                     float* outv)
{
    float a[Q];
    #pragma unroll
    for (int q = 0; q < Q; q++) a[q] = b1v;
    #pragma unroll 4
    for (int i = 0; i < 64; i++) {
        float w = sW1[i*64 + lane];
        #pragma unroll
        for (int q = 0; q < Q; q++) a[q] = fmaf(w, rl(xi[q], i), a[q]);
    }
    #pragma unroll 4
    for (int i = 0; i < 64; i++) {
        float w = sW1[(64+i)*64 + lane];
        #pragma unroll
        for (int q = 0; q < Q; q++) a[q] = fmaf(w, rl(xj[q], i), a[q]);
    }
    #pragma unroll
    for (int q = 0; q < Q; q++) a[q] = fmaxf(a[q], 0.f);
    float c[Q];
    #pragma unroll
    for (int q = 0; q < Q; q++) c[q] = b2v;
    #pragma unroll 4
    for (int i = 0; i < 64; i++) {
        float w = sW2[i*64 + lane];
        #pragma unroll
        for (int q = 0; q < Q; q++) c[q] = fmaf(w, rl(a[q], i), c[q]);
    }
    #pragma unroll
    for (int q = 0; q < Q; q++) outv[q] = fmaxf(c[q], 0.f);
}

// h = x @ enc_w + enc_b
__global__ __launch_bounds__(256) void k_enc(const float* __restrict__ x,
                                             const float* __restrict__ W,
                                             const float* __restrict__ b,
                                             float* __restrict__ h)
{
    int idx = blockIdx.x * 256 + threadIdx.x;   // over NN*64
    int j = idx & 63, n = idx >> 6;
    const float4 xr = *(const float4*)&x[n*4];
    float a = b[j];
    a = fmaf(xr.x, W[0*64+j], a);
    a = fmaf(xr.y, W[1*64+j], a);
    a = fmaf(xr.z, W[2*64+j], a);
    a = fmaf(xr.w, W[3*64+j], a);
    h[idx] = a;
}

// Per-node precompute: A = h @ W1[:64] + b1, B = h @ W1[64:]; also zero agg.
__global__ __launch_bounds__(256) void k_pre(
    const float* __restrict__ h,
    const float* __restrict__ W1, const float* __restrict__ B1,
    float* __restrict__ A, float* __restrict__ Bm, float* __restrict__ agg)
{
    __shared__ float sW[128*64];
    for (int idx = threadIdx.x; idx < 128*64; idx += 256) sW[idx] = W1[idx];
    __syncthreads();
    const int lane = threadIdx.x & 63;
    const int wid  = blockIdx.x*4 + (threadIdx.x >> 6);
    const int n0 = wid*8;                    // grid sized for single sweep
    const float b1v = B1[lane];
    float x[8], a[8], b[8];
    #pragma unroll
    for (int q = 0; q < 8; q++) {
        x[q] = h[(n0+q)*64 + lane];
        a[q] = b1v; b[q] = 0.f;
    }
    #pragma unroll 4
    for (int i = 0; i < 64; i++) {
        float wa = sW[i*64 + lane];
        float wb = sW[(64+i)*64 + lane];
        #pragma unroll
        for (int q = 0; q < 8; q++) {
            float xv = rl(x[q], i);
            a[q] = fmaf(wa, xv, a[q]);
            b[q] = fmaf(wb, xv, b[q]);
        }
    }
    #pragma unroll
    for (int q = 0; q < 8; q++) {
        A [(n0+q)*64 + lane] = a[q];
        Bm[(n0+q)*64 + lane] = b[q];
        agg[(n0+q)*64 + lane] = 0.f;
    }
}

// Per-edge: hidden = relu(A[tgt]+B[src]); m = relu(hidden@W2+b2); agg[tgt]+=m
__global__ __launch_bounds__(256) void k_edge2(
    const float* __restrict__ A, const float* __restrict__ Bm,
    const int* __restrict__ src, const int* __restrict__ tgt,
    const float* __restrict__ W2, const float* __restrict__ B2,
    float* __restrict__ agg)
{
    __shared__ float sW[64*64];
    for (int idx = threadIdx.x; idx < 64*64; idx += 256) sW[idx] = W2[idx];
    __syncthreads();
    const int lane = threadIdx.x & 63;
    const int wid  = blockIdx.x*4 + (threadIdx.x >> 6);
    const int stride = gridDim.x * 4 * 8;
    const float b2v = B2[lane];
    for (int e0 = wid*8; e0 < NE; e0 += stride) {
        int tg[8], sr[8];
        float hd[8], c[8];
        #pragma unroll
        for (int q = 0; q < 8; q++) { tg[q] = tgt[e0+q]; sr[q] = src[e0+q]; }
        #pragma unroll
        for (int q = 0; q < 8; q++)
            hd[q] = fmaxf(A[tg[q]*64 + lane] + Bm[sr[q]*64 + lane], 0.f);
        #pragma unroll
        for (int q = 0; q < 8; q++) c[q] = b2v;
        #pragma unroll 4
        for (int i = 0; i < 64; i++) {
            float w = sW[i*64 + lane];
            #pragma unroll
            for (int q = 0; q < 8; q++) c[q] = fmaf(w, rl(hd[q], i), c[q]);
        }
        #pragma unroll
        for (int q = 0; q < 8; q++)
            atomicAdd(&agg[tg[q]*64 + lane], fmaxf(c[q], 0.f));
    }
}

// node update MLP on concat(h, agg), in-place into h (single sweep)
__global__ __launch_bounds__(256) void k_update(
    float* __restrict__ h, const float* __restrict__ agg,
    const float* __restrict__ W1, const float* __restrict__ B1,
    const float* __restrict__ W2, const float* __restrict__ B2)
{
    __shared__ float sW1[128*64];
    __shared__ float sW2[64*64];
    for (int idx = threadIdx.x; idx < 128*64; idx += 256) sW1[idx] = W1[idx];
    for (int idx = threadIdx.x; idx < 64*64; idx += 256)  sW2[idx] = W2[idx];
    __syncthreads();
    const int lane = threadIdx.x & 63;
    const int wid  = blockIdx.x*4 + (threadIdx.x >> 6);
    const int n0 = wid*8;
    const float b1v = B1[lane], b2v = B2[lane];
    float xi[8], xj[8], ov[8];
    #pragma unroll
    for (int q = 0; q < 8; q++) {
        xi[q] = h[(n0+q)*64 + lane];
        xj[q] = agg[(n0+q)*64 + lane];
    }
    mlp2<8>(sW1, sW2, b1v, b2v, lane, xi, xj, ov);
    #pragma unroll
    for (int q = 0; q < 8; q++) h[(n0+q)*64 + lane] = ov[q];
}

// per-(graph,chunk) partial sums for instance-norm stats (no atomics)
__global__ __launch_bounds__(256) void k_stats(const float* __restrict__ h,
                                               float* __restrict__ psum,
                                               float* __restrict__ psq)
{
    int b = blockIdx.x >> 3, c = blockIdx.x & 7;   // 8 graphs x 8 chunks
    int j = threadIdx.x & 63, r = threadIdx.x >> 6;
    int base = b*NS + c*256;
    float s = 0.f, q = 0.f;
    for (int i = r; i < 256; i += 4) {
        float v = h[(base+i)*64 + j];
        s += v; q += v*v;
    }
    __shared__ float ls[4][64], lq[4][64];
    ls[r][j] = s; lq[r][j] = q;
    __syncthreads();
    if (r == 0) {
        s = ls[0][j]+ls[1][j]+ls[2][j]+ls[3][j];
        q = lq[0][j]+lq[1][j]+lq[2][j]+lq[3][j];
        psum[(b*8+c)*64 + j] = s;
        psq [(b*8+c)*64 + j] = q;
    }
}

__global__ __launch_bounds__(256) void k_norm(float* __restrict__ h,
                                              const float* __restrict__ psum,
                                              const float* __restrict__ psq)
{
    int idx = blockIdx.x * 256 + threadIdx.x;   // over NN*64
    int j = idx & 63; int n = idx >> 6; int b = n >> 11;
    float s = 0.f, q = 0.f;
    #pragma unroll
    for (int c = 0; c < 8; c++) {
        s += psum[(b*8+c)*64 + j];
        q += psq [(b*8+c)*64 + j];
    }
    float mean = s * (1.f/NS);
    float var  = q * (1.f/NS) - mean*mean;
    h[idx] = (h[idx] - mean) * rsqrtf(var + EPSF);
}

// X = sigmoid(h @ dec_w + dec_b); writes xbuf + d_out(+1); zeroes acc
__global__ __launch_bounds__(256) void k_dec(const float* __restrict__ h,
                                             const float* __restrict__ Wd,
                                             const float* __restrict__ bd,
                                             float* __restrict__ xbuf,
                                             float* __restrict__ out1,
                                             float* __restrict__ acc)
{
    int n = blockIdx.x * 256 + threadIdx.x;   // NN threads
    if (blockIdx.x == 0 && threadIdx.x < 2) acc[threadIdx.x] = 0.f;
    float acc0 = bd[0], acc1 = bd[1], acc2 = bd[2], acc3 = bd[3];
    const float* hr = h + n*64;
    #pragma unroll
    for (int j4 = 0; j4 < 64; j4 += 4) {
        float4 v = *(const float4*)&hr[j4];
        acc0 = fmaf(v.x, Wd[(j4+0)*4+0], acc0); acc1 = fmaf(v.x, Wd[(j4+0)*4+1], acc1);
        acc2 = fmaf(v.x, Wd[(j4+0)*4+2], acc2); acc3 = fmaf(v.x, Wd[(j4+0)*4+3], acc3);
        acc0 = fmaf(v.y, Wd[(j4+1)*4+0], acc0); acc1 = fmaf(v.y, Wd[(j4+1)*4+1], acc1);
        acc2 = fmaf(v.y, Wd[(j4+1)*4+2], acc2); acc3 = fmaf(v.y, Wd[(j4+1)*4+3], acc3);
        acc0 = fmaf(v.z, Wd[(j4+2)*4+0], acc0); acc1 = fmaf(v.z, Wd[(j4+2)*4+1], acc1);
        acc2 = fmaf(v.z, Wd[(j4+2)*4+2], acc2); acc3 = fmaf(v.z, Wd[(j4+2)*4+3], acc3);
        acc0 = fmaf(v.w, Wd[(j4+3)*4+0], acc0); acc1 = fmaf(v.w, Wd[(j4+3)*4+1], acc1);
        acc2 = fmaf(v.w, Wd[(j4+3)*4+2], acc2); acc3 = fmaf(v.w, Wd[(j4+3)*4+3], acc3);
    }
    float4 o;
    o.x = 1.f/(1.f + expf(-acc0));
    o.y = 1.f/(1.f + expf(-acc1));
    o.z = 1.f/(1.f + expf(-acc2));
    o.w = 1.f/(1.f + expf(-acc3));
    *(float4*)&xbuf[n*4] = o;
    out1[n*4+0] = o.x; out1[n*4+1] = o.y; out1[n*4+2] = o.z; out1[n*4+3] = o.w;
}

// A2 = sum over all nodes of prod_k (1 - x_k^2)
__global__ __launch_bounds__(256) void k_t2(const float* __restrict__ X,
                                            float* __restrict__ accum)
{
    int n = blockIdx.x * 256 + threadIdx.x;
    float4 x = *(const float4*)&X[n*4];
    float p = (1.f-x.x*x.x)*(1.f-x.y*x.y)*(1.f-x.z*x.z)*(1.f-x.w*x.w);
    for (int off = 32; off; off >>= 1) p += __shfl_down(p, off, 64);
    __shared__ float ws[4];
    if ((threadIdx.x & 63) == 0) ws[threadIdx.x >> 6] = p;
    __syncthreads();
    if (threadIdx.x == 0) atomicAdd(&accum[0], ws[0]+ws[1]+ws[2]+ws[3]);
}

// A3 = sum over graphs of sum_{i,j} prod_k (1 - max(x_ik, x_jk))
__global__ __launch_bounds__(256) void k_t3(const float* __restrict__ X,
                                            float* __restrict__ accum)
{
    int b = blockIdx.x >> 5, c = blockIdx.x & 31;   // 8 graphs x 32 i-chunks of 64
    __shared__ float sX[NS*4];
    const float* Xb = X + b*NS*4;
    for (int idx = threadIdx.x; idx < NS*4; idx += 256) sX[idx] = Xb[idx];
    __syncthreads();
    const float4* sX4 = (const float4*)sX;
    int il = threadIdx.x & 63, wv = threadIdx.x >> 6;
    float4 xi = sX4[c*64 + il];
    float acc = 0.f;
    #pragma unroll 4
    for (int s = 0; s < 512; s++) {
        float4 xj = sX4[wv*512 + s];
        float t = (1.f - fmaxf(xi.x, xj.x)) * (1.f - fmaxf(xi.y, xj.y))
                * (1.f - fmaxf(xi.z, xj.z)) * (1.f - fmaxf(xi.w, xj.w));
        acc += t;
    }
    for (int off = 32; off; off >>= 1) acc += __shfl_down(acc, off, 64);
    __shared__ float ws[4];
    if ((threadIdx.x & 63) == 0) ws[threadIdx.x >> 6] = acc;
    __syncthreads();
    if (threadIdx.x == 0) atomicAdd(&accum[1], ws[0]+ws[1]+ws[2]+ws[3]);
}

__global__ void k_fin(const float* __restrict__ accum, float* __restrict__ out)
{
    if (threadIdx.x == 0 && blockIdx.x == 0) {
        float A2 = accum[0], A3 = accum[1];
        float t1 = 1.f/81.f;
        float t2 = (2.f/(NS*16.f)) * (A2 / NB);
        float t3 = (A3 / ((float)NS*(float)NS)) / NB;
        out[0] = t1 - t2 + t3;
    }
}

extern "C" void kernel_launch(void* const* d_in, const int* in_sizes, int n_in,
                              void* d_out, int out_size, void* d_ws, size_t ws_size,
                              hipStream_t stream)
{
    const float* x     = (const float*)d_in[0];
    const int*   ei    = (const int*)d_in[1];
    const float* enc_w = (const float*)d_in[2];
    const float* enc_b = (const float*)d_in[3];
    const float* m1w   = (const float*)d_in[4];
    const float* m1b   = (const float*)d_in[5];
    const float* m2w   = (const float*)d_in[6];
    const float* m2b   = (const float*)d_in[7];
    const float* u1w   = (const float*)d_in[8];
    const float* u1b   = (const float*)d_in[9];
    const float* u2w   = (const float*)d_in[10];
    const float* u2b   = (const float*)d_in[11];
    const float* dw    = (const float*)d_in[12];
    const float* db    = (const float*)d_in[13];
    float* out = (float*)d_out;

    float* h    = (float*)d_ws;            // NN*64
    float* agg  = h    + NN*64;            // NN*64
    float* Apre = agg  + NN*64;            // NN*64
    float* Bpre = Apre + NN*64;            // NN*64
    float* xbuf = Bpre + NN*64;            // NN*4
    float* psum = xbuf + NN*4;             // NB*8*64
    float* psq  = psum + NB*8*64;          // NB*8*64
    float* acc  = psq  + NB*8*64;          // 2

    const int* srcv = ei;        // edge_index[0]
    const int* tgtv = ei + NE;   // edge_index[1]

    k_enc<<<NN*64/256, 256, 0, stream>>>(x, enc_w, enc_b, h);

    for (int l = 0; l < NL; l++) {
        k_pre<<<NN/(8*4), 256, 0, stream>>>(h, m1w + l*128*64, m1b + l*64,
                                            Apre, Bpre, agg);
        k_edge2<<<2048, 256, 0, stream>>>(Apre, Bpre, srcv, tgtv,
                                          m2w + l*64*64, m2b + l*64, agg);
        k_update<<<NN/(8*4), 256, 0, stream>>>(h, agg,
                                               u1w + l*128*64, u1b + l*64,
                                               u2w + l*64*64,  u2b + l*64);
        k_stats<<<NB*8, 256, 0, stream>>>(h, psum, psq);
        k_norm<<<NN*64/256, 256, 0, stream>>>(h, psum, psq);
    }

    k_dec<<<NN/256, 256, 0, stream>>>(h, dw, db, xbuf, out + 1, acc);
    k_t2<<<NN/256, 256, 0, stream>>>(xbuf, acc);
    k_t3<<<NB*32, 256, 0, stream>>>(xbuf, acc);
    k_fin<<<1, 64, 0, stream>>>(acc, out);
}

// Round 3
// 410.468 us; speedup vs baseline: 2.4759x; 1.3375x over previous
//
#include <hip/hip_runtime.h>
#include <hip/hip_fp16.h>
#include <math.h>

#define NB 8
#define NS 2048
#define NH 64
#define NL 3
#define NN (NB*NS)       // 16384 nodes
#define NE (NN*16)       // 262144 edges
#define EPSF 1e-5f
#define HSTR 68          // padded LDS row stride (floats): (4m+k)&31 -> <=2-way, free

typedef float  f32x4 __attribute__((ext_vector_type(4)));
typedef _Float16 f16x8 __attribute__((ext_vector_type(8)));
union F8 { f16x8 v; unsigned u[4]; };

__device__ __forceinline__ float rl(float v, int i) {
    return __int_as_float(__builtin_amdgcn_readlane(__float_as_int(v), i));
}

__device__ __forceinline__ unsigned pk2h(float a, float b) {
    __half2 hh = __floats2half2_rn(a, b);
    unsigned u; __builtin_memcpy(&u, &hh, 4); return u;
}

// Two-layer MLP on concat(xi, xj) (readlane version, used by k_update)
template<int Q>
__device__ __forceinline__ void mlp2(const float* __restrict__ sW1,
                                     const float* __restrict__ sW2,
                                     float b1v, float b2v, int lane,
                                     const float* xi, const float* xj,
                                     float* outv)
{
    float a[Q];
    #pragma unroll
    for (int q = 0; q < Q; q++) a[q] = b1v;
    #pragma unroll 4
    for (int i = 0; i < 64; i++) {
        float w = sW1[i*64 + lane];
        #pragma unroll
        for (int q = 0; q < Q; q++) a[q] = fmaf(w, rl(xi[q], i), a[q]);
    }
    #pragma unroll 4
    for (int i = 0; i < 64; i++) {
        float w = sW1[(64+i)*64 + lane];
        #pragma unroll
        for (int q = 0; q < Q; q++) a[q] = fmaf(w, rl(xj[q], i), a[q]);
    }
    #pragma unroll
    for (int q = 0; q < Q; q++) a[q] = fmaxf(a[q], 0.f);
    float c[Q];
    #pragma unroll
    for (int q = 0; q < Q; q++) c[q] = b2v;
    #pragma unroll 4
    for (int i = 0; i < 64; i++) {
        float w = sW2[i*64 + lane];
        #pragma unroll
        for (int q = 0; q < Q; q++) c[q] = fmaf(w, rl(a[q], i), c[q]);
    }
    #pragma unroll
    for (int q = 0; q < Q; q++) outv[q] = fmaxf(c[q], 0.f);
}

// Fused: (enc OR instance-norm of h) -> write h; A = h@W1a + b1, B = h@W1b; zero agg;
// block 0 zeroes the stats buffer the following k_update will atomically fill.
__global__ __launch_bounds__(256) void k_pre(
    const float* __restrict__ x,
    const float* __restrict__ encW, const float* __restrict__ encB,
    float* __restrict__ h,
    const float* __restrict__ W1, const float* __restrict__ B1,
    float* __restrict__ A, float* __restrict__ Bm, float* __restrict__ agg,
    const float* __restrict__ gin, float* __restrict__ gz, int first)
{
    __shared__ float sW[128*64];
    __shared__ float sMean[64], sRstd[64];
    for (int idx = threadIdx.x; idx < 128*64; idx += 256) sW[idx] = W1[idx];
    if (threadIdx.x < 64) {
        if (first) { sMean[threadIdx.x] = 0.f; sRstd[threadIdx.x] = 1.f; }
        else {
            int b = (int)(blockIdx.x >> 6);   // 64 blocks (32 nodes each) per graph
            float s  = gin[b*64 + threadIdx.x];
            float qq = gin[NB*64 + b*64 + threadIdx.x];
            float mean = s * (1.f/NS);
            float var  = qq * (1.f/NS) - mean*mean;
            sMean[threadIdx.x] = mean;
            sRstd[threadIdx.x] = rsqrtf(var + EPSF);
        }
    }
    if (blockIdx.x == 0)
        for (int i = threadIdx.x; i < 2*NB*64; i += 256) gz[i] = 0.f;
    __syncthreads();
    const int lane = threadIdx.x & 63;
    const int wid  = blockIdx.x*4 + (threadIdx.x >> 6);
    const int n0 = wid*8;
    const float b1v = B1[lane];
    const float mn = sMean[lane], rs = sRstd[lane];
    float xv[8], a[8], b[8];
    if (first) {
        float we0 = encW[0*64+lane], we1 = encW[64+lane];
        float we2 = encW[128+lane], we3 = encW[192+lane];
        float be = encB[lane];
        #pragma unroll
        for (int q = 0; q < 8; q++) {
            float4 xr = *(const float4*)&x[(n0+q)*4];
            float v = be;
            v = fmaf(xr.x, we0, v); v = fmaf(xr.y, we1, v);
            v = fmaf(xr.z, we2, v); v = fmaf(xr.w, we3, v);
            xv[q] = v;
            h[(n0+q)*64 + lane] = v;
        }
    } else {
        #pragma unroll
        for (int q = 0; q < 8; q++) {
            float v = (h[(n0+q)*64 + lane] - mn) * rs;
            xv[q] = v;
            h[(n0+q)*64 + lane] = v;
        }
    }
    #pragma unroll
    for (int q = 0; q < 8; q++) { a[q] = b1v; b[q] = 0.f; }
    #pragma unroll 4
    for (int i = 0; i < 64; i++) {
        float wa = sW[i*64 + lane];
        float wb = sW[(64+i)*64 + lane];
        #pragma unroll
        for (int q = 0; q < 8; q++) {
            float xs = rl(xv[q], i);
            a[q] = fmaf(wa, xs, a[q]);
            b[q] = fmaf(wb, xs, b[q]);
        }
    }
    #pragma unroll
    for (int q = 0; q < 8; q++) {
        A [(n0+q)*64 + lane] = a[q];
        Bm[(n0+q)*64 + lane] = b[q];
        agg[(n0+q)*64 + lane] = 0.f;
    }
}

// MFMA edge kernel: per wave, 32-edge tile.
// hidden = relu(A[tgt]+B[src]) -> LDS (fp32, stride 68) -> f16 A-frags;
// W2 pre-staged as f16 B-frags in registers; 16x16x32 f16 MFMA; epilogue +b2,relu, atomicAdd.
__global__ __launch_bounds__(256, 4) void k_edge3(
    const float* __restrict__ A, const float* __restrict__ Bm,
    const int* __restrict__ src, const int* __restrict__ tgt,
    const float* __restrict__ W2, const float* __restrict__ B2,
    float* __restrict__ agg)
{
    __shared__ float sHd[4*32*HSTR];   // 34816 B; first 4096 floats double as W2 stage
    __shared__ int   sTi[4*32];
    for (int i = threadIdx.x; i < 64*64; i += 256) sHd[i] = W2[i];
    __syncthreads();
    const int lane = threadIdx.x & 63;
    const int wv   = threadIdx.x >> 6;
    const int col  = lane & 15, quad = lane >> 4;
    F8 bf[4][2];
    #pragma unroll
    for (int nt = 0; nt < 4; nt++)
        #pragma unroll
        for (int ks = 0; ks < 2; ks++)
            #pragma unroll
            for (int jj = 0; jj < 4; jj++) {
                int k = ks*32 + quad*8 + jj*2;
                bf[nt][ks].u[jj] = pk2h(sHd[k*64 + nt*16 + col],
                                        sHd[(k+1)*64 + nt*16 + col]);
            }
    float b2v[4];
    #pragma unroll
    for (int nt = 0; nt < 4; nt++) b2v[nt] = B2[nt*16 + col];
    __syncthreads();   // done with W2 stage region
    float* hd = &sHd[wv*32*HSTR];
    int*   ti = &sTi[wv*32];

    for (int tile = blockIdx.x*4 + wv; tile < NE/32; tile += gridDim.x*4) {
        int e0 = tile*32;
        if (lane < 32) ti[lane] = tgt[e0 + lane];
        #pragma unroll 8
        for (int e = 0; e < 32; e++) {
            int tg = tgt[e0+e], sr = src[e0+e];
            hd[e*HSTR + lane] = fmaxf(A[tg*64 + lane] + Bm[sr*64 + lane], 0.f);
        }
        // wave-private LDS region: compiler inserts lgkmcnt waits, no barrier needed
        #pragma unroll
        for (int mt = 0; mt < 2; mt++) {
            const float* hr = &hd[(mt*16 + col)*HSTR + quad*8];
            float4 a0 = *(const float4*)&hr[0];
            float4 a1 = *(const float4*)&hr[4];
            float4 a2 = *(const float4*)&hr[32];
            float4 a3 = *(const float4*)&hr[36];
            F8 af0, af1;
            af0.u[0] = pk2h(a0.x, a0.y); af0.u[1] = pk2h(a0.z, a0.w);
            af0.u[2] = pk2h(a1.x, a1.y); af0.u[3] = pk2h(a1.z, a1.w);
            af1.u[0] = pk2h(a2.x, a2.y); af1.u[1] = pk2h(a2.z, a2.w);
            af1.u[2] = pk2h(a3.x, a3.y); af1.u[3] = pk2h(a3.z, a3.w);
            int tg0 = ti[mt*16 + quad*4 + 0];
            int tg1 = ti[mt*16 + quad*4 + 1];
            int tg2 = ti[mt*16 + quad*4 + 2];
            int tg3 = ti[mt*16 + quad*4 + 3];
            #pragma unroll
            for (int nt = 0; nt < 4; nt++) {
                f32x4 acc = __builtin_amdgcn_mfma_f32_16x16x32_f16(
                                af0.v, bf[nt][0].v, (f32x4){0.f,0.f,0.f,0.f}, 0, 0, 0);
                acc = __builtin_amdgcn_mfma_f32_16x16x32_f16(
                                af1.v, bf[nt][1].v, acc, 0, 0, 0);
                int ch = nt*16 + col;
                atomicAdd(&agg[tg0*64 + ch], fmaxf(acc.x + b2v[nt], 0.f));
                atomicAdd(&agg[tg1*64 + ch], fmaxf(acc.y + b2v[nt], 0.f));
                atomicAdd(&agg[tg2*64 + ch], fmaxf(acc.z + b2v[nt], 0.f));
                atomicAdd(&agg[tg3*64 + ch], fmaxf(acc.w + b2v[nt], 0.f));
            }
        }
    }
}

// update MLP -> h (raw); per-block stats atomically into gout; block0 zeroes acc[0..3]
__global__ __launch_bounds__(256) void k_update(
    float* __restrict__ h, const float* __restrict__ agg,
    const float* __restrict__ W1, const float* __restrict__ B1,
    const float* __restrict__ W2, const float* __restrict__ B2,
    float* __restrict__ gout, float* __restrict__ acc3)
{
    __shared__ float sW1[128*64];
    __shared__ float sW2[64*64];
    for (int idx = threadIdx.x; idx < 128*64; idx += 256) sW1[idx] = W1[idx];
    for (int idx = threadIdx.x; idx < 64*64; idx += 256)  sW2[idx] = W2[idx];
    __syncthreads();
    const int lane = threadIdx.x & 63;
    const int wv   = threadIdx.x >> 6;
    const int n0 = (blockIdx.x*4 + wv)*8;
    const float b1v = B1[lane], b2v = B2[lane];
    float xi[8], xj[8], ov[8];
    #pragma unroll
    for (int q = 0; q < 8; q++) {
        xi[q] = h[(n0+q)*64 + lane];
        xj[q] = agg[(n0+q)*64 + lane];
    }
    mlp2<8>(sW1, sW2, b1v, b2v, lane, xi, xj, ov);
    float s = 0.f, sq = 0.f;
    #pragma unroll
    for (int q = 0; q < 8; q++) {
        h[(n0+q)*64 + lane] = ov[q];
        s += ov[q]; sq += ov[q]*ov[q];
    }
    __shared__ float ls[4][64], lq2[4][64];
    ls[wv][lane] = s; lq2[wv][lane] = sq;
    __syncthreads();
    if (wv == 0) {
        s  = ls[0][lane]+ls[1][lane]+ls[2][lane]+ls[3][lane];
        sq = lq2[0][lane]+lq2[1][lane]+lq2[2][lane]+lq2[3][lane];
        int b = (int)(blockIdx.x >> 6);
        atomicAdd(&gout[b*64 + lane], s);
        atomicAdd(&gout[NB*64 + b*64 + lane], sq);
    }
    if (blockIdx.x == 0 && threadIdx.x < 4) acc3[threadIdx.x] = 0.f;
}

// Fused: instance-norm (from g) + decode + sigmoid + t2-term reduction
__global__ __launch_bounds__(256) void k_dec(
    const float* __restrict__ h, const float* __restrict__ Wd, const float* __restrict__ bd,
    const float* __restrict__ g, float* __restrict__ xbuf, float* __restrict__ out1,
    float* __restrict__ accum)
{
    int n = blockIdx.x*256 + threadIdx.x;
    int b = n >> 11;
    __shared__ float sM[64], sR[64];
    __shared__ float sWd[256];
    if (threadIdx.x < 64) {
        float s  = g[b*64 + threadIdx.x];
        float qq = g[NB*64 + b*64 + threadIdx.x];
        float mean = s * (1.f/NS);
        float var  = qq * (1.f/NS) - mean*mean;
        sM[threadIdx.x] = mean; sR[threadIdx.x] = rsqrtf(var + EPSF);
    }
    for (int i = threadIdx.x; i < 256; i += 256) sWd[i] = Wd[i];
    __syncthreads();
    float a0 = bd[0], a1 = bd[1], a2 = bd[2], a3 = bd[3];
    const float* hr = h + n*64;
    #pragma unroll 8
    for (int k = 0; k < 64; k++) {
        float v = (hr[k] - sM[k]) * sR[k];
        a0 = fmaf(v, sWd[k*4+0], a0);
        a1 = fmaf(v, sWd[k*4+1], a1);
        a2 = fmaf(v, sWd[k*4+2], a2);
        a3 = fmaf(v, sWd[k*4+3], a3);
    }
    float4 o;
    o.x = 1.f/(1.f + expf(-a0));
    o.y = 1.f/(1.f + expf(-a1));
    o.z = 1.f/(1.f + expf(-a2));
    o.w = 1.f/(1.f + expf(-a3));
    *(float4*)&xbuf[n*4] = o;
    out1[n*4+0] = o.x; out1[n*4+1] = o.y; out1[n*4+2] = o.z; out1[n*4+3] = o.w;
    // t2 term
    float p = (1.f-o.x*o.x)*(1.f-o.y*o.y)*(1.f-o.z*o.z)*(1.f-o.w*o.w);
    for (int off = 32; off; off >>= 1) p += __shfl_down(p, off, 64);
    __shared__ float ws[4];
    if ((threadIdx.x & 63) == 0) ws[threadIdx.x >> 6] = p;
    __syncthreads();
    if (threadIdx.x == 0) atomicAdd(&accum[0], ws[0]+ws[1]+ws[2]+ws[3]);
}

// t3 pairwise term + final loss via last-block ticket
__global__ __launch_bounds__(256) void k_t3(const float* __restrict__ X,
                                            float* __restrict__ accum,
                                            float* __restrict__ out)
{
    int b = blockIdx.x >> 5, c = blockIdx.x & 31;
    __shared__ float sX[NS*4];
    const float* Xb = X + b*NS*4;
    for (int idx = threadIdx.x; idx < NS*4; idx += 256) sX[idx] = Xb[idx];
    __syncthreads();
    const float4* sX4 = (const float4*)sX;
    int il = threadIdx.x & 63, wv = threadIdx.x >> 6;
    float4 xi = sX4[c*64 + il];
    float acc = 0.f;
    #pragma unroll 4
    for (int s = 0; s < 512; s++) {
        float4 xj = sX4[wv*512 + s];
        acc += (1.f - fmaxf(xi.x, xj.x)) * (1.f - fmaxf(xi.y, xj.y))
             * (1.f - fmaxf(xi.z, xj.z)) * (1.f - fmaxf(xi.w, xj.w));
    }
    for (int off = 32; off; off >>= 1) acc += __shfl_down(acc, off, 64);
    __shared__ float ws[4];
    if (il == 0) ws[wv] = acc;
    __syncthreads();
    if (threadIdx.x == 0) {
        atomicAdd(&accum[1], ws[0]+ws[1]+ws[2]+ws[3]);
        __threadfence();
        unsigned t = atomicAdd((unsigned int*)&accum[2], 1u);
        if (t == (unsigned)(NB*32 - 1)) {
            float A2 = __hip_atomic_load(&accum[0], __ATOMIC_ACQUIRE, __HIP_MEMORY_SCOPE_AGENT);
            float A3 = __hip_atomic_load(&accum[1], __ATOMIC_ACQUIRE, __HIP_MEMORY_SCOPE_AGENT);
            float t1 = 1.f/81.f;
            float t2 = (2.f/(NS*16.f)) * (A2 / NB);
            float t3 = (A3 / ((float)NS*(float)NS)) / NB;
            out[0] = t1 - t2 + t3;
        }
    }
}

extern "C" void kernel_launch(void* const* d_in, const int* in_sizes, int n_in,
                              void* d_out, int out_size, void* d_ws, size_t ws_size,
                              hipStream_t stream)
{
    const float* x     = (const float*)d_in[0];
    const int*   ei    = (const int*)d_in[1];
    const float* enc_w = (const float*)d_in[2];
    const float* enc_b = (const float*)d_in[3];
    const float* m1w   = (const float*)d_in[4];
    const float* m1b   = (const float*)d_in[5];
    const float* m2w   = (const float*)d_in[6];
    const float* m2b   = (const float*)d_in[7];
    const float* u1w   = (const float*)d_in[8];
    const float* u1b   = (const float*)d_in[9];
    const float* u2w   = (const float*)d_in[10];
    const float* u2b   = (const float*)d_in[11];
    const float* dw    = (const float*)d_in[12];
    const float* db    = (const float*)d_in[13];
    float* out = (float*)d_out;

    float* h    = (float*)d_ws;            // NN*64
    float* agg  = h    + NN*64;            // NN*64
    float* Apre = agg  + NN*64;            // NN*64
    float* Bpre = Apre + NN*64;            // NN*64
    float* xbuf = Bpre + NN*64;            // NN*4
    float* g0   = xbuf + NN*4;             // 2*NB*64 (sum, sq)
    float* g1   = g0   + 2*NB*64;          // 2*NB*64
    float* acc  = g1   + 2*NB*64;          // 4: A2, A3, ticket, pad

    const int* srcv = ei;        // edge_index[0]
    const int* tgtv = ei + NE;   // edge_index[1]
    float* gbuf[2] = {g0, g1};

    for (int l = 0; l < NL; l++) {
        k_pre<<<NN/32, 256, 0, stream>>>(x, enc_w, enc_b, h,
                                         m1w + l*128*64, m1b + l*64,
                                         Apre, Bpre, agg,
                                         l ? gbuf[(l+1)&1] : g0, gbuf[l&1], l == 0);
        k_edge3<<<1024, 256, 0, stream>>>(Apre, Bpre, srcv, tgtv,
                                          m2w + l*64*64, m2b + l*64, agg);
        k_update<<<NN/32, 256, 0, stream>>>(h, agg,
                                            u1w + l*128*64, u1b + l*64,
                                            u2w + l*64*64,  u2b + l*64,
                                            gbuf[l&1], acc);
    }

    k_dec<<<NN/256, 256, 0, stream>>>(h, dw, db, g0, xbuf, out + 1, acc);
    k_t3<<<NB*32, 256, 0, stream>>>(xbuf, acc, out);
}

// Round 4
// 354.387 us; speedup vs baseline: 2.8677x; 1.1582x over previous
//
#include <hip/hip_runtime.h>
#include <hip/hip_fp16.h>
#include <math.h>

#define NB 8
#define NS 2048
#define NH 64
#define NL 3
#define NN (NB*NS)       // 16384 nodes
#define NE (NN*16)       // 262144 edges
#define EPSF 1e-5f
#define HSTR 68          // padded LDS row stride (floats)

typedef float  f32x4 __attribute__((ext_vector_type(4)));
typedef _Float16 f16x8 __attribute__((ext_vector_type(8)));
union F8 { f16x8 v; unsigned u[4]; };

__device__ __forceinline__ float rl(float v, int i) {
    return __int_as_float(__builtin_amdgcn_readlane(__float_as_int(v), i));
}
__device__ __forceinline__ unsigned pk2h(float a, float b) {
    __half2 hh = __floats2half2_rn(a, b);
    unsigned u; __builtin_memcpy(&u, &hh, 4); return u;
}

// Two-layer MLP on concat(xi, xj) (readlane version, used by k_update)
template<int Q>
__device__ __forceinline__ void mlp2(const float* __restrict__ sW1,
                                     const float* __restrict__ sW2,
                                     float b1v, float b2v, int lane,
                                     const float* xi, const float* xj,
                                     float* outv)
{
    float a[Q];
    #pragma unroll
    for (int q = 0; q < Q; q++) a[q] = b1v;
    #pragma unroll 4
    for (int i = 0; i < 64; i++) {
        float w = sW1[i*64 + lane];
        #pragma unroll
        for (int q = 0; q < Q; q++) a[q] = fmaf(w, rl(xi[q], i), a[q]);
    }
    #pragma unroll 4
    for (int i = 0; i < 64; i++) {
        float w = sW1[(64+i)*64 + lane];
        #pragma unroll
        for (int q = 0; q < Q; q++) a[q] = fmaf(w, rl(xj[q], i), a[q]);
    }
    #pragma unroll
    for (int q = 0; q < Q; q++) a[q] = fmaxf(a[q], 0.f);
    float c[Q];
    #pragma unroll
    for (int q = 0; q < Q; q++) c[q] = b2v;
    #pragma unroll 4
    for (int i = 0; i < 64; i++) {
        float w = sW2[i*64 + lane];
        #pragma unroll
        for (int q = 0; q < Q; q++) c[q] = fmaf(w, rl(a[q], i), c[q]);
    }
    #pragma unroll
    for (int q = 0; q < Q; q++) outv[q] = fmaxf(c[q], 0.f);
}

// Fused: (enc OR instance-norm of h) -> h; A = h@W1a + b1, B = h@W1b;
// first: zero agg (edge3 atomics need it), zero deg/cursor (CSR build).
// scat: scatter edges into CSR order (off/cur ready from previous kernels).
__global__ __launch_bounds__(256) void k_pre(
    const float* __restrict__ x,
    const float* __restrict__ encW, const float* __restrict__ encB,
    float* __restrict__ h,
    const float* __restrict__ W1, const float* __restrict__ B1,
    float* __restrict__ A, float* __restrict__ Bm, float* __restrict__ agg,
    const float* __restrict__ gin, float* __restrict__ gz, int first,
    const int* __restrict__ srcv, const int* __restrict__ tgtv,
    int* __restrict__ deg, int* __restrict__ cur,
    const int* __restrict__ off, int* __restrict__ ssrc, int scat)
{
    if (first) {   // zero deg + cursor (contiguous 2*NN ints)
        int gid = blockIdx.x*256 + threadIdx.x;
        for (int i = gid; i < 2*NN; i += 512*256) deg[i] = 0;
    }
    if (scat) {    // scatter into CSR (off built by previous kernel, cur zeroed at l0)
        int gid = blockIdx.x*256 + threadIdx.x;
        for (int e = gid; e < NE; e += 512*256) {
            int t = tgtv[e];
            int p = off[t] + atomicAdd(&cur[t], 1);
            ssrc[p] = srcv[e];
        }
    }
    __shared__ float sW[128*64];
    __shared__ float sMean[64], sRstd[64];
    for (int idx = threadIdx.x; idx < 128*64; idx += 256) sW[idx] = W1[idx];
    if (threadIdx.x < 64) {
        if (first) { sMean[threadIdx.x] = 0.f; sRstd[threadIdx.x] = 1.f; }
        else {
            int b = (int)(blockIdx.x >> 6);
            float s  = gin[b*64 + threadIdx.x];
            float qq = gin[NB*64 + b*64 + threadIdx.x];
            float mean = s * (1.f/NS);
            float var  = qq * (1.f/NS) - mean*mean;
            sMean[threadIdx.x] = mean;
            sRstd[threadIdx.x] = rsqrtf(var + EPSF);
        }
    }
    if (blockIdx.x == 0)
        for (int i = threadIdx.x; i < 2*NB*64; i += 256) gz[i] = 0.f;
    __syncthreads();
    const int lane = threadIdx.x & 63;
    const int wid  = blockIdx.x*4 + (threadIdx.x >> 6);
    const int n0 = wid*8;
    const float b1v = B1[lane];
    const float mn = sMean[lane], rs = sRstd[lane];
    float xv[8], a[8], b[8];
    if (first) {
        float we0 = encW[0*64+lane], we1 = encW[64+lane];
        float we2 = encW[128+lane], we3 = encW[192+lane];
        float be = encB[lane];
        #pragma unroll
        for (int q = 0; q < 8; q++) {
            float4 xr = *(const float4*)&x[(n0+q)*4];
            float v = be;
            v = fmaf(xr.x, we0, v); v = fmaf(xr.y, we1, v);
            v = fmaf(xr.z, we2, v); v = fmaf(xr.w, we3, v);
            xv[q] = v;
            h[(n0+q)*64 + lane] = v;
        }
    } else {
        #pragma unroll
        for (int q = 0; q < 8; q++) {
            float v = (h[(n0+q)*64 + lane] - mn) * rs;
            xv[q] = v;
            h[(n0+q)*64 + lane] = v;
        }
    }
    #pragma unroll
    for (int q = 0; q < 8; q++) { a[q] = b1v; b[q] = 0.f; }
    #pragma unroll 4
    for (int i = 0; i < 64; i++) {
        float wa = sW[i*64 + lane];
        float wb = sW[(64+i)*64 + lane];
        #pragma unroll
        for (int q = 0; q < 8; q++) {
            float xs = rl(xv[q], i);
            a[q] = fmaf(wa, xs, a[q]);
            b[q] = fmaf(wb, xs, b[q]);
        }
    }
    #pragma unroll
    for (int q = 0; q < 8; q++) {
        A [(n0+q)*64 + lane] = a[q];
        Bm[(n0+q)*64 + lane] = b[q];
        if (first) agg[(n0+q)*64 + lane] = 0.f;
    }
}

// Layer-0 MFMA edge kernel (atomic aggregation) + CSR histogram piggyback.
__global__ __launch_bounds__(256, 4) void k_edge3(
    const float* __restrict__ A, const float* __restrict__ Bm,
    const int* __restrict__ src, const int* __restrict__ tgt,
    const float* __restrict__ W2, const float* __restrict__ B2,
    float* __restrict__ agg, int* __restrict__ deg)
{
    __shared__ float sHd[4*32*HSTR];
    __shared__ int   sTi[4*32];
    for (int i = threadIdx.x; i < 64*64; i += 256) sHd[i] = W2[i];
    __syncthreads();
    const int lane = threadIdx.x & 63;
    const int wv   = threadIdx.x >> 6;
    const int col  = lane & 15, quad = lane >> 4;
    F8 bf[4][2];
    #pragma unroll
    for (int nt = 0; nt < 4; nt++)
        #pragma unroll
        for (int ks = 0; ks < 2; ks++)
            #pragma unroll
            for (int jj = 0; jj < 4; jj++) {
                int k = ks*32 + quad*8 + jj*2;
                bf[nt][ks].u[jj] = pk2h(sHd[k*64 + nt*16 + col],
                                        sHd[(k+1)*64 + nt*16 + col]);
            }
    float b2v[4];
    #pragma unroll
    for (int nt = 0; nt < 4; nt++) b2v[nt] = B2[nt*16 + col];
    __syncthreads();
    float* hd = &sHd[wv*32*HSTR];
    int*   ti = &sTi[wv*32];

    for (int tile = blockIdx.x*4 + wv; tile < NE/32; tile += gridDim.x*4) {
        int e0 = tile*32;
        if (lane < 32) {
            int tv = tgt[e0 + lane];
            ti[lane] = tv;
            atomicAdd(&deg[tv], 1);     // CSR histogram (each edge once)
        }
        #pragma unroll 8
        for (int e = 0; e < 32; e++) {
            int tg = tgt[e0+e], sr = src[e0+e];
            hd[e*HSTR + lane] = fmaxf(A[tg*64 + lane] + Bm[sr*64 + lane], 0.f);
        }
        #pragma unroll
        for (int mt = 0; mt < 2; mt++) {
            const float* hr = &hd[(mt*16 + col)*HSTR + quad*8];
            float4 a0 = *(const float4*)&hr[0];
            float4 a1 = *(const float4*)&hr[4];
            float4 a2 = *(const float4*)&hr[32];
            float4 a3 = *(const float4*)&hr[36];
            F8 af0, af1;
            af0.u[0] = pk2h(a0.x, a0.y); af0.u[1] = pk2h(a0.z, a0.w);
            af0.u[2] = pk2h(a1.x, a1.y); af0.u[3] = pk2h(a1.z, a1.w);
            af1.u[0] = pk2h(a2.x, a2.y); af1.u[1] = pk2h(a2.z, a2.w);
            af1.u[2] = pk2h(a3.x, a3.y); af1.u[3] = pk2h(a3.z, a3.w);
            int tg0 = ti[mt*16 + quad*4 + 0];
            int tg1 = ti[mt*16 + quad*4 + 1];
            int tg2 = ti[mt*16 + quad*4 + 2];
            int tg3 = ti[mt*16 + quad*4 + 3];
            #pragma unroll
            for (int nt = 0; nt < 4; nt++) {
                f32x4 acc = __builtin_amdgcn_mfma_f32_16x16x32_f16(
                                af0.v, bf[nt][0].v, (f32x4){0.f,0.f,0.f,0.f}, 0, 0, 0);
                acc = __builtin_amdgcn_mfma_f32_16x16x32_f16(
                                af1.v, bf[nt][1].v, acc, 0, 0, 0);
                int ch = nt*16 + col;
                atomicAdd(&agg[tg0*64 + ch], fmaxf(acc.x + b2v[nt], 0.f));
                atomicAdd(&agg[tg1*64 + ch], fmaxf(acc.y + b2v[nt], 0.f));
                atomicAdd(&agg[tg2*64 + ch], fmaxf(acc.z + b2v[nt], 0.f));
                atomicAdd(&agg[tg3*64 + ch], fmaxf(acc.w + b2v[nt], 0.f));
            }
        }
    }
}

// CSR edge kernel (layers 1,2): one wave per target, register-direct fragments,
// per-edge relu(+b2) then masked in-register row reduction; plain stores, NO atomics.
__global__ __launch_bounds__(256) void k_edge4(
    const float* __restrict__ A, const float* __restrict__ Bm,
    const int* __restrict__ off, const int* __restrict__ ssrc,
    const float* __restrict__ W2, const float* __restrict__ B2,
    float* __restrict__ agg)
{
    __shared__ float sW[64*64];
    for (int i = threadIdx.x; i < 64*64; i += 256) sW[i] = W2[i];
    __syncthreads();
    const int lane = threadIdx.x & 63;
    const int col = lane & 15, quad = lane >> 4;
    F8 bf[4][2];
    #pragma unroll
    for (int nt = 0; nt < 4; nt++)
        #pragma unroll
        for (int ks = 0; ks < 2; ks++)
            #pragma unroll
            for (int jj = 0; jj < 4; jj++) {
                int k = ks*32 + quad*8 + jj*2;
                bf[nt][ks].u[jj] = pk2h(sW[k*64 + nt*16 + col],
                                        sW[(k+1)*64 + nt*16 + col]);
            }
    float b2v[4];
    #pragma unroll
    for (int nt = 0; nt < 4; nt++) b2v[nt] = B2[nt*16 + col];

    const int wid = blockIdx.x*4 + (threadIdx.x >> 6);
    const int nwv = gridDim.x*4;
    for (int t = wid; t < NN; t += nwv) {
        int start = off[t], end = off[t+1];
        const float* ar = &A[t*64 + quad*8];
        float4 a0 = *(const float4*)&ar[0];
        float4 a1 = *(const float4*)&ar[4];
        float4 a2 = *(const float4*)&ar[32];
        float4 a3 = *(const float4*)&ar[36];
        float cs[4] = {0.f, 0.f, 0.f, 0.f};
        for (int s0 = start; s0 < end; s0 += 16) {
            int v = end - s0;                       // valid rows this round
            int cc = col < v-1 ? col : v-1;
            int sr = ssrc[s0 + cc];
            const float* br = &Bm[sr*64 + quad*8];
            float4 b0 = *(const float4*)&br[0];
            float4 b1 = *(const float4*)&br[4];
            float4 b2_ = *(const float4*)&br[32];
            float4 b3 = *(const float4*)&br[36];
            F8 af0, af1;
            af0.u[0] = pk2h(fmaxf(a0.x+b0.x,0.f), fmaxf(a0.y+b0.y,0.f));
            af0.u[1] = pk2h(fmaxf(a0.z+b0.z,0.f), fmaxf(a0.w+b0.w,0.f));
            af0.u[2] = pk2h(fmaxf(a1.x+b1.x,0.f), fmaxf(a1.y+b1.y,0.f));
            af0.u[3] = pk2h(fmaxf(a1.z+b1.z,0.f), fmaxf(a1.w+b1.w,0.f));
            af1.u[0] = pk2h(fmaxf(a2.x+b2_.x,0.f), fmaxf(a2.y+b2_.y,0.f));
            af1.u[1] = pk2h(fmaxf(a2.z+b2_.z,0.f), fmaxf(a2.w+b2_.w,0.f));
            af1.u[2] = pk2h(fmaxf(a3.x+b3.x,0.f), fmaxf(a3.y+b3.y,0.f));
            af1.u[3] = pk2h(fmaxf(a3.z+b3.z,0.f), fmaxf(a3.w+b3.w,0.f));
            #pragma unroll
            for (int nt = 0; nt < 4; nt++) {
                f32x4 acc = __builtin_amdgcn_mfma_f32_16x16x32_f16(
                                af0.v, bf[nt][0].v, (f32x4){0.f,0.f,0.f,0.f}, 0, 0, 0);
                acc = __builtin_amdgcn_mfma_f32_16x16x32_f16(
                                af1.v, bf[nt][1].v, acc, 0, 0, 0);
                // per-edge bias+relu BEFORE aggregation; mask pad rows
                float r0 = (quad*4+0 < v) ? fmaxf(acc.x + b2v[nt], 0.f) : 0.f;
                float r1 = (quad*4+1 < v) ? fmaxf(acc.y + b2v[nt], 0.f) : 0.f;
                float r2 = (quad*4+2 < v) ? fmaxf(acc.z + b2v[nt], 0.f) : 0.f;
                float r3 = (quad*4+3 < v) ? fmaxf(acc.w + b2v[nt], 0.f) : 0.f;
                cs[nt] += (r0 + r1) + (r2 + r3);
            }
        }
        #pragma unroll
        for (int nt = 0; nt < 4; nt++) {
            float vv = cs[nt];
            vv += __shfl_down(vv, 32, 64);
            vv += __shfl_down(vv, 16, 64);
            cs[nt] = vv;
        }
        if (lane < 16) {
            agg[t*64 +  0 + lane] = cs[0];
            agg[t*64 + 16 + lane] = cs[1];
            agg[t*64 + 32 + lane] = cs[2];
            agg[t*64 + 48 + lane] = cs[3];
        }
    }
}

// update MLP -> h; per-block stats atomically into gout; block0 zeroes acc[0..3];
// do_scan: block 0 additionally builds exclusive prefix off[] from deg[].
__global__ __launch_bounds__(256) void k_update(
    float* __restrict__ h, const float* __restrict__ agg,
    const float* __restrict__ W1, const float* __restrict__ B1,
    const float* __restrict__ W2, const float* __restrict__ B2,
    float* __restrict__ gout, float* __restrict__ acc3,
    const int* __restrict__ deg, int* __restrict__ off, int do_scan)
{
    __shared__ float sW1[128*64];
    __shared__ float sW2[64*64];
    for (int idx = threadIdx.x; idx < 128*64; idx += 256) sW1[idx] = W1[idx];
    for (int idx = threadIdx.x; idx < 64*64; idx += 256)  sW2[idx] = W2[idx];
    __syncthreads();
    const int lane = threadIdx.x & 63;
    const int wv   = threadIdx.x >> 6;
    const int n0 = (blockIdx.x*4 + wv)*8;
    const float b1v = B1[lane], b2v = B2[lane];
    float xi[8], xj[8], ov[8];
    #pragma unroll
    for (int q = 0; q < 8; q++) {
        xi[q] = h[(n0+q)*64 + lane];
        xj[q] = agg[(n0+q)*64 + lane];
    }
    mlp2<8>(sW1, sW2, b1v, b2v, lane, xi, xj, ov);
    float s = 0.f, sq = 0.f;
    #pragma unroll
    for (int q = 0; q < 8; q++) {
        h[(n0+q)*64 + lane] = ov[q];
        s += ov[q]; sq += ov[q]*ov[q];
    }
    __shared__ float ls[4][64], lq2[4][64];
    ls[wv][lane] = s; lq2[wv][lane] = sq;
    __syncthreads();
    if (wv == 0) {
        s  = ls[0][lane]+ls[1][lane]+ls[2][lane]+ls[3][lane];
        sq = lq2[0][lane]+lq2[1][lane]+lq2[2][lane]+lq2[3][lane];
        int b = (int)(blockIdx.x >> 6);
        atomicAdd(&gout[b*64 + lane], s);
        atomicAdd(&gout[NB*64 + b*64 + lane], sq);
    }
    if (blockIdx.x == 0 && threadIdx.x < 4) acc3[threadIdx.x] = 0.f;
    if (do_scan && blockIdx.x == 0) {
        __syncthreads();
        int* sp = (int*)sW1;     // reuse LDS
        int tid = threadIdx.x;
        int ssum = 0;
        for (int j = 0; j < 64; j++) ssum += deg[tid*64 + j];
        sp[tid] = ssum;
        __syncthreads();
        for (int d = 1; d < 256; d <<= 1) {
            int mine = sp[tid];
            int other = (tid >= d) ? sp[tid - d] : 0;
            __syncthreads();
            sp[tid] = mine + other;
            __syncthreads();
        }
        int run = (tid > 0) ? sp[tid-1] : 0;   // exclusive prefix of this chunk
        for (int j = 0; j < 64; j++) {
            off[tid*64 + j] = run;
            run += deg[tid*64 + j];
        }
        if (tid == 255) off[NN] = run;
    }
}

// Fused: instance-norm + decode + sigmoid + t2-term reduction
__global__ __launch_bounds__(256) void k_dec(
    const float* __restrict__ h, const float* __restrict__ Wd, const float* __restrict__ bd,
    const float* __restrict__ g, float* __restrict__ xbuf, float* __restrict__ out1,
    float* __restrict__ accum)
{
    int n = blockIdx.x*256 + threadIdx.x;
    int b = n >> 11;
    __shared__ float sM[64], sR[64];
    __shared__ float sWd[256];
    if (threadIdx.x < 64) {
        float s  = g[b*64 + threadIdx.x];
        float qq = g[NB*64 + b*64 + threadIdx.x];
        float mean = s * (1.f/NS);
        float var  = qq * (1.f/NS) - mean*mean;
        sM[threadIdx.x] = mean; sR[threadIdx.x] = rsqrtf(var + EPSF);
    }
    for (int i = threadIdx.x; i < 256; i += 256) sWd[i] = Wd[i];
    __syncthreads();
    float a0 = bd[0], a1 = bd[1], a2 = bd[2], a3 = bd[3];
    const float* hr = h + n*64;
    #pragma unroll 8
    for (int k = 0; k < 64; k++) {
        float v = (hr[k] - sM[k]) * sR[k];
        a0 = fmaf(v, sWd[k*4+0], a0);
        a1 = fmaf(v, sWd[k*4+1], a1);
        a2 = fmaf(v, sWd[k*4+2], a2);
        a3 = fmaf(v, sWd[k*4+3], a3);
    }
    float4 o;
    o.x = 1.f/(1.f + expf(-a0));
    o.y = 1.f/(1.f + expf(-a1));
    o.z = 1.f/(1.f + expf(-a2));
    o.w = 1.f/(1.f + expf(-a3));
    *(float4*)&xbuf[n*4] = o;
    out1[n*4+0] = o.x; out1[n*4+1] = o.y; out1[n*4+2] = o.z; out1[n*4+3] = o.w;
    float p = (1.f-o.x*o.x)*(1.f-o.y*o.y)*(1.f-o.z*o.z)*(1.f-o.w*o.w);
    for (int offs = 32; offs; offs >>= 1) p += __shfl_down(p, offs, 64);
    __shared__ float ws[4];
    if ((threadIdx.x & 63) == 0) ws[threadIdx.x >> 6] = p;
    __syncthreads();
    if (threadIdx.x == 0) atomicAdd(&accum[0], ws[0]+ws[1]+ws[2]+ws[3]);
}

// t3 pairwise term + final loss via last-block ticket
__global__ __launch_bounds__(256) void k_t3(const float* __restrict__ X,
                                            float* __restrict__ accum,
                                            float* __restrict__ out)
{
    int b = blockIdx.x >> 5, c = blockIdx.x & 31;
    __shared__ float sX[NS*4];
    const float* Xb = X + b*NS*4;
    for (int idx = threadIdx.x; idx < NS*4; idx += 256) sX[idx] = Xb[idx];
    __syncthreads();
    const float4* sX4 = (const float4*)sX;
    int il = threadIdx.x & 63, wv = threadIdx.x >> 6;
    float4 xi = sX4[c*64 + il];
    float acc = 0.f;
    #pragma unroll 4
    for (int s = 0; s < 512; s++) {
        float4 xj = sX4[wv*512 + s];
        acc += (1.f - fmaxf(xi.x, xj.x)) * (1.f - fmaxf(xi.y, xj.y))
             * (1.f - fmaxf(xi.z, xj.z)) * (1.f - fmaxf(xi.w, xj.w));
    }
    for (int offs = 32; offs; offs >>= 1) acc += __shfl_down(acc, offs, 64);
    __shared__ float ws[4];
    if (il == 0) ws[wv] = acc;
    __syncthreads();
    if (threadIdx.x == 0) {
        atomicAdd(&accum[1], ws[0]+ws[1]+ws[2]+ws[3]);
        __threadfence();
        unsigned t = atomicAdd((unsigned int*)&accum[2], 1u);
        if (t == (unsigned)(NB*32 - 1)) {
            float A2 = __hip_atomic_load(&accum[0], __ATOMIC_ACQUIRE, __HIP_MEMORY_SCOPE_AGENT);
            float A3 = __hip_atomic_load(&accum[1], __ATOMIC_ACQUIRE, __HIP_MEMORY_SCOPE_AGENT);
            float t1 = 1.f/81.f;
            float t2 = (2.f/(NS*16.f)) * (A2 / NB);
            float t3 = (A3 / ((float)NS*(float)NS)) / NB;
            out[0] = t1 - t2 + t3;
        }
    }
}

extern "C" void kernel_launch(void* const* d_in, const int* in_sizes, int n_in,
                              void* d_out, int out_size, void* d_ws, size_t ws_size,
                              hipStream_t stream)
{
    const float* x     = (const float*)d_in[0];
    const int*   ei    = (const int*)d_in[1];
    const float* enc_w = (const float*)d_in[2];
    const float* enc_b = (const float*)d_in[3];
    const float* m1w   = (const float*)d_in[4];
    const float* m1b   = (const float*)d_in[5];
    const float* m2w   = (const float*)d_in[6];
    const float* m2b   = (const float*)d_in[7];
    const float* u1w   = (const float*)d_in[8];
    const float* u1b   = (const float*)d_in[9];
    const float* u2w   = (const float*)d_in[10];
    const float* u2b   = (const float*)d_in[11];
    const float* dw    = (const float*)d_in[12];
    const float* db    = (const float*)d_in[13];
    float* out = (float*)d_out;

    float* h    = (float*)d_ws;            // NN*64
    float* agg  = h    + NN*64;            // NN*64
    float* Apre = agg  + NN*64;            // NN*64
    float* Bpre = Apre + NN*64;            // NN*64
    float* g0   = Bpre + NN*64;            // 2*NB*64
    float* g1   = g0   + 2*NB*64;          // 2*NB*64
    float* acc  = g1   + 2*NB*64;          // 4
    int*   deg  = (int*)(acc + 4);         // NN
    int*   cur  = deg + NN;                // NN  (contiguous with deg for zeroing)
    int*   off  = cur + NN;                // NN+1
    int*   ssrc = off + NN + 1;            // NE
    float* xbuf = Apre;                    // alias: Apre dead after last edge kernel

    const int* srcv = ei;
    const int* tgtv = ei + NE;
    float* gbuf[2] = {g0, g1};

    for (int l = 0; l < NL; l++) {
        k_pre<<<NN/32, 256, 0, stream>>>(x, enc_w, enc_b, h,
                                         m1w + l*128*64, m1b + l*64,
                                         Apre, Bpre, agg,
                                         l ? gbuf[(l+1)&1] : g0, gbuf[l&1], l == 0,
                                         srcv, tgtv, deg, cur, off, ssrc, l == 1);
        if (l == 0)
            k_edge3<<<1024, 256, 0, stream>>>(Apre, Bpre, srcv, tgtv,
                                              m2w, m2b, agg, deg);
        else
            k_edge4<<<1024, 256, 0, stream>>>(Apre, Bpre, off, ssrc,
                                              m2w + l*64*64, m2b + l*64, agg);
        k_update<<<NN/32, 256, 0, stream>>>(h, agg,
                                            u1w + l*128*64, u1b + l*64,
                                            u2w + l*64*64,  u2b + l*64,
                                            gbuf[l&1], acc, deg, off, l == 0);
    }

    k_dec<<<NN/256, 256, 0, stream>>>(h, dw, db, g0, xbuf, out + 1, acc);
    k_t3<<<NB*32, 256, 0, stream>>>(xbuf, acc, out);
}

// Round 6
// 263.408 us; speedup vs baseline: 3.8581x; 1.3454x over previous
//
#include <hip/hip_runtime.h>
#include <hip/hip_fp16.h>
#include <math.h>

#define NB 8
#define NS 2048
#define NH 64
#define NL 3
#define NN (NB*NS)       // 16384 nodes
#define NE (NN*16)       // 262144 edges
#define EPSF 1e-5f

typedef float  f32x4 __attribute__((ext_vector_type(4)));
typedef _Float16 f16x8 __attribute__((ext_vector_type(8)));
union F8 { f16x8 v; unsigned u[4]; };

__device__ __forceinline__ float rl(float v, int i) {
    return __int_as_float(__builtin_amdgcn_readlane(__float_as_int(v), i));
}
__device__ __forceinline__ unsigned pk2h(float a, float b) {
    __half2 hh = __floats2half2_rn(a, b);
    unsigned u; __builtin_memcpy(&u, &hh, 4); return u;
}

// zero deg+cur (contiguous) and acc
__global__ __launch_bounds__(256) void k_init(int* __restrict__ deg2,
                                              float* __restrict__ acc)
{
    int i = blockIdx.x*256 + threadIdx.x;
    if (i < 2*NN) deg2[i] = 0;
    if (i < 4) acc[i] = 0.f;
}

// Layer 0: enc -> h; A = h@W1a + b1, B = h@W1b; CSR histogram; zero g0.
__global__ __launch_bounds__(256) void k_pre0(
    const float* __restrict__ x,
    const float* __restrict__ encW, const float* __restrict__ encB,
    float* __restrict__ h,
    const float* __restrict__ W1, const float* __restrict__ B1,
    float* __restrict__ A, float* __restrict__ Bm,
    float* __restrict__ gz,
    const int* __restrict__ tgtv, int* __restrict__ deg)
{
    {   // CSR histogram: each edge exactly once (grid 512 blocks)
        int gid = blockIdx.x*256 + threadIdx.x;
        atomicAdd(&deg[tgtv[gid]], 1);
        atomicAdd(&deg[tgtv[gid + 512*256]], 1);
    }
    __shared__ float sW[128*64];
    for (int idx = threadIdx.x; idx < 128*64; idx += 256) sW[idx] = W1[idx];
    if (blockIdx.x == 0)
        for (int i = threadIdx.x; i < 2*NB*64; i += 256) gz[i] = 0.f;
    __syncthreads();
    const int lane = threadIdx.x & 63;
    const int wid  = blockIdx.x*4 + (threadIdx.x >> 6);
    const int n0 = wid*8;
    const float b1v = B1[lane];
    float xv[8], a[8], b[8];
    float we0 = encW[lane], we1 = encW[64+lane];
    float we2 = encW[128+lane], we3 = encW[192+lane];
    float be = encB[lane];
    #pragma unroll
    for (int q = 0; q < 8; q++) {
        float4 xr = *(const float4*)&x[(n0+q)*4];
        float v = be;
        v = fmaf(xr.x, we0, v); v = fmaf(xr.y, we1, v);
        v = fmaf(xr.z, we2, v); v = fmaf(xr.w, we3, v);
        xv[q] = v;
        h[(n0+q)*64 + lane] = v;
    }
    #pragma unroll
    for (int q = 0; q < 8; q++) { a[q] = b1v; b[q] = 0.f; }
    #pragma unroll 4
    for (int i = 0; i < 64; i++) {
        float wa = sW[i*64 + lane];
        float wb = sW[(64+i)*64 + lane];
        #pragma unroll
        for (int q = 0; q < 8; q++) {
            float xs = rl(xv[q], i);
            a[q] = fmaf(wa, xs, a[q]);
            b[q] = fmaf(wb, xs, b[q]);
        }
    }
    #pragma unroll
    for (int q = 0; q < 8; q++) {
        A [(n0+q)*64 + lane] = a[q];
        Bm[(n0+q)*64 + lane] = b[q];
    }
}

// single-block exclusive scan of deg -> off
__global__ __launch_bounds__(256) void k_scan(const int* __restrict__ deg,
                                              int* __restrict__ off)
{
    __shared__ int sp[256];
    int t = threadIdx.x;
    int s = 0;
    for (int j = 0; j < 64; j++) s += deg[t*64 + j];
    sp[t] = s;
    __syncthreads();
    for (int d = 1; d < 256; d <<= 1) {
        int mine = sp[t];
        int oth = (t >= d) ? sp[t-d] : 0;
        __syncthreads();
        sp[t] = mine + oth;
        __syncthreads();
    }
    int run = t ? sp[t-1] : 0;
    for (int j = 0; j < 64; j++) { off[t*64 + j] = run; run += deg[t*64 + j]; }
    if (t == 255) off[NN] = run;
}

// scatter src into CSR order
__global__ __launch_bounds__(256) void k_scat(
    const int* __restrict__ srcv, const int* __restrict__ tgtv,
    const int* __restrict__ off, int* __restrict__ cur, int* __restrict__ ssrc)
{
    int gid = blockIdx.x*256 + threadIdx.x;
    #pragma unroll
    for (int it = 0; it < 2; it++) {
        int e = gid + it*512*256;
        int t = tgtv[e];
        int p = off[t] + atomicAdd(&cur[t], 1);
        ssrc[p] = srcv[e];
    }
}

// CSR edge kernel: one wave per target, register-direct fragments, plain stores.
__global__ __launch_bounds__(256) void k_edge4(
    const float* __restrict__ A, const float* __restrict__ Bm,
    const int* __restrict__ off, const int* __restrict__ ssrc,
    const float* __restrict__ W2, const float* __restrict__ B2,
    float* __restrict__ agg)
{
    __shared__ float sW[64*64];
    for (int i = threadIdx.x; i < 64*64; i += 256) sW[i] = W2[i];
    __syncthreads();
    const int lane = threadIdx.x & 63;
    const int col = lane & 15, quad = lane >> 4;
    F8 bf[4][2];
    #pragma unroll
    for (int nt = 0; nt < 4; nt++)
        #pragma unroll
        for (int ks = 0; ks < 2; ks++)
            #pragma unroll
            for (int jj = 0; jj < 4; jj++) {
                int k = ks*32 + quad*8 + jj*2;
                bf[nt][ks].u[jj] = pk2h(sW[k*64 + nt*16 + col],
                                        sW[(k+1)*64 + nt*16 + col]);
            }
    float b2v[4];
    #pragma unroll
    for (int nt = 0; nt < 4; nt++) b2v[nt] = B2[nt*16 + col];

    const int wid = blockIdx.x*4 + (threadIdx.x >> 6);
    const int nwv = gridDim.x*4;
    for (int t = wid; t < NN; t += nwv) {
        int start = off[t], end = off[t+1];
        const float* ar = &A[t*64 + quad*8];
        float4 a0 = *(const float4*)&ar[0];
        float4 a1 = *(const float4*)&ar[4];
        float4 a2 = *(const float4*)&ar[32];
        float4 a3 = *(const float4*)&ar[36];
        float cs[4] = {0.f, 0.f, 0.f, 0.f};
        for (int s0 = start; s0 < end; s0 += 16) {
            int v = end - s0;
            int cc = col < v-1 ? col : v-1;
            int sr = ssrc[s0 + cc];
            const float* br = &Bm[sr*64 + quad*8];
            float4 b0 = *(const float4*)&br[0];
            float4 b1 = *(const float4*)&br[4];
            float4 b2_ = *(const float4*)&br[32];
            float4 b3 = *(const float4*)&br[36];
            F8 af0, af1;
            af0.u[0] = pk2h(fmaxf(a0.x+b0.x,0.f), fmaxf(a0.y+b0.y,0.f));
            af0.u[1] = pk2h(fmaxf(a0.z+b0.z,0.f), fmaxf(a0.w+b0.w,0.f));
            af0.u[2] = pk2h(fmaxf(a1.x+b1.x,0.f), fmaxf(a1.y+b1.y,0.f));
            af0.u[3] = pk2h(fmaxf(a1.z+b1.z,0.f), fmaxf(a1.w+b1.w,0.f));
            af1.u[0] = pk2h(fmaxf(a2.x+b2_.x,0.f), fmaxf(a2.y+b2_.y,0.f));
            af1.u[1] = pk2h(fmaxf(a2.z+b2_.z,0.f), fmaxf(a2.w+b2_.w,0.f));
            af1.u[2] = pk2h(fmaxf(a3.x+b3.x,0.f), fmaxf(a3.y+b3.y,0.f));
            af1.u[3] = pk2h(fmaxf(a3.z+b3.z,0.f), fmaxf(a3.w+b3.w,0.f));
            #pragma unroll
            for (int nt = 0; nt < 4; nt++) {
                f32x4 acc = __builtin_amdgcn_mfma_f32_16x16x32_f16(
                                af0.v, bf[nt][0].v, (f32x4){0.f,0.f,0.f,0.f}, 0, 0, 0);
                acc = __builtin_amdgcn_mfma_f32_16x16x32_f16(
                                af1.v, bf[nt][1].v, acc, 0, 0, 0);
                float r0 = (quad*4+0 < v) ? fmaxf(acc.x + b2v[nt], 0.f) : 0.f;
                float r1 = (quad*4+1 < v) ? fmaxf(acc.y + b2v[nt], 0.f) : 0.f;
                float r2 = (quad*4+2 < v) ? fmaxf(acc.z + b2v[nt], 0.f) : 0.f;
                float r3 = (quad*4+3 < v) ? fmaxf(acc.w + b2v[nt], 0.f) : 0.f;
                cs[nt] += (r0 + r1) + (r2 + r3);
            }
        }
        #pragma unroll
        for (int nt = 0; nt < 4; nt++) {
            float vv = cs[nt];
            vv += __shfl_down(vv, 32, 64);
            vv += __shfl_down(vv, 16, 64);
            cs[nt] = vv;
        }
        if (lane < 16) {
            agg[t*64 +  0 + lane] = cs[0];
            agg[t*64 + 16 + lane] = cs[1];
            agg[t*64 + 32 + lane] = cs[2];
            agg[t*64 + 48 + lane] = cs[3];
        }
    }
}

// MFMA update MLP: h <- relu(W2^T relu(W1^T [h;agg] + b1) + b2); stats -> gout.
// Hardened: 16B-aligned f16 LDS, explicit vector components, barrier between stages.
__global__ __launch_bounds__(256) void k_updateM(
    float* __restrict__ h, const float* __restrict__ agg,
    const float* __restrict__ W1, const float* __restrict__ B1,
    const float* __restrict__ W2, const float* __restrict__ B2,
    float* __restrict__ gout)
{
    alignas(16) __shared__ _Float16 sW1u[8192];   // [ks4][nt4][qd4][col16][j8]
    alignas(16) __shared__ _Float16 sW2u[4096];   // [ks2][nt4][qd4][col16][j8]
    alignas(16) __shared__ float sHid[4][16*68];
    __shared__ float sSum[4][64], sSq[4][64];
    for (int idx = threadIdx.x; idx < 8192; idx += 256) {
        int k = idx >> 6, n = idx & 63;
        int ks = k >> 5, qd = (k >> 3) & 3, j = k & 7, nt = n >> 4, cl = n & 15;
        sW1u[(((ks*4+nt)*4+qd)*16+cl)*8 + j] = (_Float16)W1[idx];
    }
    for (int idx = threadIdx.x; idx < 4096; idx += 256) {
        int k = idx >> 6, n = idx & 63;
        int ks = k >> 5, qd = (k >> 3) & 3, j = k & 7, nt = n >> 4, cl = n & 15;
        sW2u[(((ks*4+nt)*4+qd)*16+cl)*8 + j] = (_Float16)W2[idx];
    }
    __syncthreads();
    const int lane = threadIdx.x & 63;
    const int wv = threadIdx.x >> 6;
    const int col = lane & 15, quad = lane >> 4;
    const int n0w = blockIdx.x*64 + wv*16;
    const float* hp = &h[(n0w+col)*64 + quad*8];
    const float* ap = &agg[(n0w+col)*64 + quad*8];
    float4 h0 = *(const float4*)&hp[0];
    float4 h1 = *(const float4*)&hp[4];
    float4 h2 = *(const float4*)&hp[32];
    float4 h3 = *(const float4*)&hp[36];
    float4 g0 = *(const float4*)&ap[0];
    float4 g1 = *(const float4*)&ap[4];
    float4 g2 = *(const float4*)&ap[32];
    float4 g3 = *(const float4*)&ap[36];
    F8 af[4];
    af[0].u[0] = pk2h(h0.x, h0.y); af[0].u[1] = pk2h(h0.z, h0.w);
    af[0].u[2] = pk2h(h1.x, h1.y); af[0].u[3] = pk2h(h1.z, h1.w);
    af[1].u[0] = pk2h(h2.x, h2.y); af[1].u[1] = pk2h(h2.z, h2.w);
    af[1].u[2] = pk2h(h3.x, h3.y); af[1].u[3] = pk2h(h3.z, h3.w);
    af[2].u[0] = pk2h(g0.x, g0.y); af[2].u[1] = pk2h(g0.z, g0.w);
    af[2].u[2] = pk2h(g1.x, g1.y); af[2].u[3] = pk2h(g1.z, g1.w);
    af[3].u[0] = pk2h(g2.x, g2.y); af[3].u[1] = pk2h(g2.z, g2.w);
    af[3].u[2] = pk2h(g3.x, g3.y); af[3].u[3] = pk2h(g3.z, g3.w);
    float b1v[4], b2v[4];
    #pragma unroll
    for (int nt = 0; nt < 4; nt++) { b1v[nt] = B1[nt*16+col]; b2v[nt] = B2[nt*16+col]; }
    float* hid = &sHid[wv][0];
    #pragma unroll
    for (int nt = 0; nt < 4; nt++) {
        f32x4 acc = {0.f,0.f,0.f,0.f};
        #pragma unroll
        for (int ks = 0; ks < 4; ks++) {
            F8 bf; bf.v = *(const f16x8*)&sW1u[(((ks*4+nt)*4+quad)*16+col)*8];
            acc = __builtin_amdgcn_mfma_f32_16x16x32_f16(af[ks].v, bf.v, acc, 0, 0, 0);
        }
        hid[(quad*4+0)*68 + nt*16+col] = fmaxf(acc.x + b1v[nt], 0.f);
        hid[(quad*4+1)*68 + nt*16+col] = fmaxf(acc.y + b1v[nt], 0.f);
        hid[(quad*4+2)*68 + nt*16+col] = fmaxf(acc.z + b1v[nt], 0.f);
        hid[(quad*4+3)*68 + nt*16+col] = fmaxf(acc.w + b1v[nt], 0.f);
    }
    __syncthreads();   // guarantee LDS writes visible before cross-lane reads
    // layer 2: hidden (cross-lane, same wave) -> A-frags
    const float* hr = &hid[col*68 + quad*8];
    float4 q0 = *(const float4*)&hr[0];
    float4 q1 = *(const float4*)&hr[4];
    float4 q2 = *(const float4*)&hr[32];
    float4 q3 = *(const float4*)&hr[36];
    F8 e0, e1;
    e0.u[0] = pk2h(q0.x, q0.y); e0.u[1] = pk2h(q0.z, q0.w);
    e0.u[2] = pk2h(q1.x, q1.y); e0.u[3] = pk2h(q1.z, q1.w);
    e1.u[0] = pk2h(q2.x, q2.y); e1.u[1] = pk2h(q2.z, q2.w);
    e1.u[2] = pk2h(q3.x, q3.y); e1.u[3] = pk2h(q3.z, q3.w);
    float ss[4], sq[4];
    #pragma unroll
    for (int nt = 0; nt < 4; nt++) {
        f32x4 acc = {0.f,0.f,0.f,0.f};
        F8 bf; bf.v = *(const f16x8*)&sW2u[(((0*4+nt)*4+quad)*16+col)*8];
        acc = __builtin_amdgcn_mfma_f32_16x16x32_f16(e0.v, bf.v, acc, 0, 0, 0);
        bf.v = *(const f16x8*)&sW2u[(((1*4+nt)*4+quad)*16+col)*8];
        acc = __builtin_amdgcn_mfma_f32_16x16x32_f16(e1.v, bf.v, acc, 0, 0, 0);
        float o0 = fmaxf(acc.x + b2v[nt], 0.f);
        float o1 = fmaxf(acc.y + b2v[nt], 0.f);
        float o2 = fmaxf(acc.z + b2v[nt], 0.f);
        float o3 = fmaxf(acc.w + b2v[nt], 0.f);
        h[(n0w + quad*4 + 0)*64 + nt*16 + col] = o0;
        h[(n0w + quad*4 + 1)*64 + nt*16 + col] = o1;
        h[(n0w + quad*4 + 2)*64 + nt*16 + col] = o2;
        h[(n0w + quad*4 + 3)*64 + nt*16 + col] = o3;
        ss[nt] = (o0 + o1) + (o2 + o3);
        sq[nt] = (o0*o0 + o1*o1) + (o2*o2 + o3*o3);
    }
    #pragma unroll
    for (int nt = 0; nt < 4; nt++) {
        float v = ss[nt];
        v += __shfl_down(v, 32, 64); v += __shfl_down(v, 16, 64);
        float w2 = sq[nt];
        w2 += __shfl_down(w2, 32, 64); w2 += __shfl_down(w2, 16, 64);
        if (lane < 16) { sSum[wv][nt*16+lane] = v; sSq[wv][nt*16+lane] = w2; }
    }
    __syncthreads();
    if (threadIdx.x < 128) {
        int ch = threadIdx.x & 63, hf = threadIdx.x >> 6;
        int b = (int)(blockIdx.x >> 5);
        if (hf == 0) {
            float t_ = sSum[0][ch]+sSum[1][ch]+sSum[2][ch]+sSum[3][ch];
            atomicAdd(&gout[b*64 + ch], t_);
        } else {
            float t_ = sSq[0][ch]+sSq[1][ch]+sSq[2][ch]+sSq[3][ch];
            atomicAdd(&gout[NB*64 + b*64 + ch], t_);
        }
    }
}

// MFMA pre (layers 1,2): normalize h (write back), A = h@W1a+b1, B = h@W1b; zero gz.
__global__ __launch_bounds__(256) void k_preM(
    float* __restrict__ h,
    const float* __restrict__ W1, const float* __restrict__ B1,
    float* __restrict__ A, float* __restrict__ Bm,
    const float* __restrict__ gin, float* __restrict__ gz)
{
    alignas(16) __shared__ _Float16 sWp[8192];   // [ks2][nt8][qd4][col16][j8]
    __shared__ float sMean[64], sRstd[64];
    for (int idx = threadIdx.x; idx < 8192; idx += 256) {
        int k = idx >> 7, n = idx & 127;
        float val = (n < 64) ? W1[k*64 + n] : W1[(64+k)*64 + (n-64)];
        int ks = k >> 5, qd = (k >> 3) & 3, j = k & 7, nt = n >> 4, cl = n & 15;
        sWp[(((ks*8+nt)*4+qd)*16+cl)*8 + j] = (_Float16)val;
    }
    if (threadIdx.x < 64) {
        int b = (int)(blockIdx.x >> 5);
        float s  = gin[b*64 + threadIdx.x];
        float qq = gin[NB*64 + b*64 + threadIdx.x];
        float mean = s * (1.f/NS);
        float var  = qq * (1.f/NS) - mean*mean;
        sMean[threadIdx.x] = mean;
        sRstd[threadIdx.x] = rsqrtf(var + EPSF);
    }
    if (blockIdx.x == 0)
        for (int i = threadIdx.x; i < 2*NB*64; i += 256) gz[i] = 0.f;
    __syncthreads();
    const int lane = threadIdx.x & 63;
    const int wv = threadIdx.x >> 6;
    const int col = lane & 15, quad = lane >> 4;
    const int n0w = blockIdx.x*64 + wv*16;
    float* hp = &h[(n0w+col)*64 + quad*8];
    float xv[16];
    *(float4*)&xv[0]  = *(const float4*)&hp[0];
    *(float4*)&xv[4]  = *(const float4*)&hp[4];
    *(float4*)&xv[8]  = *(const float4*)&hp[32];
    *(float4*)&xv[12] = *(const float4*)&hp[36];
    #pragma unroll
    for (int t2 = 0; t2 < 8; t2++) {
        int f = quad*8 + t2;
        xv[t2] = (xv[t2] - sMean[f]) * sRstd[f];
    }
    #pragma unroll
    for (int t2 = 0; t2 < 8; t2++) {
        int f = 32 + quad*8 + t2;
        xv[8+t2] = (xv[8+t2] - sMean[f]) * sRstd[f];
    }
    *(float4*)&hp[0]  = *(float4*)&xv[0];
    *(float4*)&hp[4]  = *(float4*)&xv[4];
    *(float4*)&hp[32] = *(float4*)&xv[8];
    *(float4*)&hp[36] = *(float4*)&xv[12];
    F8 af0, af1;
    af0.u[0] = pk2h(xv[0],  xv[1]);  af0.u[1] = pk2h(xv[2],  xv[3]);
    af0.u[2] = pk2h(xv[4],  xv[5]);  af0.u[3] = pk2h(xv[6],  xv[7]);
    af1.u[0] = pk2h(xv[8],  xv[9]);  af1.u[1] = pk2h(xv[10], xv[11]);
    af1.u[2] = pk2h(xv[12], xv[13]); af1.u[3] = pk2h(xv[14], xv[15]);
    float b1v[4];
    #pragma unroll
    for (int nt = 0; nt < 4; nt++) b1v[nt] = B1[nt*16+col];
    #pragma unroll
    for (int nt = 0; nt < 8; nt++) {
        f32x4 acc = {0.f,0.f,0.f,0.f};
        F8 bf; bf.v = *(const f16x8*)&sWp[(((0*8+nt)*4+quad)*16+col)*8];
        acc = __builtin_amdgcn_mfma_f32_16x16x32_f16(af0.v, bf.v, acc, 0, 0, 0);
        bf.v = *(const f16x8*)&sWp[(((1*8+nt)*4+quad)*16+col)*8];
        acc = __builtin_amdgcn_mfma_f32_16x16x32_f16(af1.v, bf.v, acc, 0, 0, 0);
        if (nt < 4) {
            float bb = b1v[nt];
            A[(n0w + quad*4 + 0)*64 + nt*16 + col] = acc.x + bb;
            A[(n0w + quad*4 + 1)*64 + nt*16 + col] = acc.y + bb;
            A[(n0w + quad*4 + 2)*64 + nt*16 + col] = acc.z + bb;
            A[(n0w + quad*4 + 3)*64 + nt*16 + col] = acc.w + bb;
        } else {
            Bm[(n0w + quad*4 + 0)*64 + (nt-4)*16 + col] = acc.x;
            Bm[(n0w + quad*4 + 1)*64 + (nt-4)*16 + col] = acc.y;
            Bm[(n0w + quad*4 + 2)*64 + (nt-4)*16 + col] = acc.z;
            Bm[(n0w + quad*4 + 3)*64 + (nt-4)*16 + col] = acc.w;
        }
    }
}

// Fused: instance-norm + decode + sigmoid + t2-term reduction
__global__ __launch_bounds__(256) void k_dec(
    const float* __restrict__ h, const float* __restrict__ Wd, const float* __restrict__ bd,
    const float* __restrict__ g, float* __restrict__ xbuf, float* __restrict__ out1,
    float* __restrict__ accum)
{
    int n = blockIdx.x*256 + threadIdx.x;
    int b = n >> 11;
    __shared__ float sM[64], sR[64];
    __shared__ float sWd[256];
    if (threadIdx.x < 64) {
        float s  = g[b*64 + threadIdx.x];
        float qq = g[NB*64 + b*64 + threadIdx.x];
        float mean = s * (1.f/NS);
        float var  = qq * (1.f/NS) - mean*mean;
        sM[threadIdx.x] = mean; sR[threadIdx.x] = rsqrtf(var + EPSF);
    }
    for (int i = threadIdx.x; i < 256; i += 256) sWd[i] = Wd[i];
    __syncthreads();
    float a0 = bd[0], a1 = bd[1], a2 = bd[2], a3 = bd[3];
    const float* hr = h + n*64;
    #pragma unroll 8
    for (int k = 0; k < 64; k++) {
        float v = (hr[k] - sM[k]) * sR[k];
        a0 = fmaf(v, sWd[k*4+0], a0);
        a1 = fmaf(v, sWd[k*4+1], a1);
        a2 = fmaf(v, sWd[k*4+2], a2);
        a3 = fmaf(v, sWd[k*4+3], a3);
    }
    float4 o;
    o.x = 1.f/(1.f + expf(-a0));
    o.y = 1.f/(1.f + expf(-a1));
    o.z = 1.f/(1.f + expf(-a2));
    o.w = 1.f/(1.f + expf(-a3));
    *(float4*)&xbuf[n*4] = o;
    out1[n*4+0] = o.x; out1[n*4+1] = o.y; out1[n*4+2] = o.z; out1[n*4+3] = o.w;
    float p = (1.f-o.x*o.x)*(1.f-o.y*o.y)*(1.f-o.z*o.z)*(1.f-o.w*o.w);
    for (int offs = 32; offs; offs >>= 1) p += __shfl_down(p, offs, 64);
    __shared__ float ws[4];
    if ((threadIdx.x & 63) == 0) ws[threadIdx.x >> 6] = p;
    __syncthreads();
    if (threadIdx.x == 0) atomicAdd(&accum[0], ws[0]+ws[1]+ws[2]+ws[3]);
}

// t3 pairwise term + final loss via last-block ticket
__global__ __launch_bounds__(256) void k_t3(const float* __restrict__ X,
                                            float* __restrict__ accum,
                                            float* __restrict__ out)
{
    int b = blockIdx.x >> 5, c = blockIdx.x & 31;
    __shared__ float sX[NS*4];
    const float* Xb = X + b*NS*4;
    for (int idx = threadIdx.x; idx < NS*4; idx += 256) sX[idx] = Xb[idx];
    __syncthreads();
    const float4* sX4 = (const float4*)sX;
    int il = threadIdx.x & 63, wv = threadIdx.x >> 6;
    float4 xi = sX4[c*64 + il];
    float acc = 0.f;
    #pragma unroll 4
    for (int s = 0; s < 512; s++) {
        float4 xj = sX4[wv*512 + s];
        acc += (1.f - fmaxf(xi.x, xj.x)) * (1.f - fmaxf(xi.y, xj.y))
             * (1.f - fmaxf(xi.z, xj.z)) * (1.f - fmaxf(xi.w, xj.w));
    }
    for (int offs = 32; offs; offs >>= 1) acc += __shfl_down(acc, offs, 64);
    __shared__ float ws[4];
    if (il == 0) ws[wv] = acc;
    __syncthreads();
    if (threadIdx.x == 0) {
        atomicAdd(&accum[1], ws[0]+ws[1]+ws[2]+ws[3]);
        __threadfence();
        unsigned t = atomicAdd((unsigned int*)&accum[2], 1u);
        if (t == (unsigned)(NB*32 - 1)) {
            float A2 = __hip_atomic_load(&accum[0], __ATOMIC_ACQUIRE, __HIP_MEMORY_SCOPE_AGENT);
            float A3 = __hip_atomic_load(&accum[1], __ATOMIC_ACQUIRE, __HIP_MEMORY_SCOPE_AGENT);
            float t1 = 1.f/81.f;
            float t2 = (2.f/(NS*16.f)) * (A2 / NB);
            float t3 = (A3 / ((float)NS*(float)NS)) / NB;
            out[0] = t1 - t2 + t3;
        }
    }
}

extern "C" void kernel_launch(void* const* d_in, const int* in_sizes, int n_in,
                              void* d_out, int out_size, void* d_ws, size_t ws_size,
                              hipStream_t stream)
{
    const float* x     = (const float*)d_in[0];
    const int*   ei    = (const int*)d_in[1];
    const float* enc_w = (const float*)d_in[2];
    const float* enc_b = (const float*)d_in[3];
    const float* m1w   = (const float*)d_in[4];
    const float* m1b   = (const float*)d_in[5];
    const float* m2w   = (const float*)d_in[6];
    const float* m2b   = (const float*)d_in[7];
    const float* u1w   = (const float*)d_in[8];
    const float* u1b   = (const float*)d_in[9];
    const float* u2w   = (const float*)d_in[10];
    const float* u2b   = (const float*)d_in[11];
    const float* dw    = (const float*)d_in[12];
    const float* db    = (const float*)d_in[13];
    float* out = (float*)d_out;

    float* h    = (float*)d_ws;            // NN*64
    float* agg  = h    + NN*64;            // NN*64
    float* Apre = agg  + NN*64;            // NN*64
    float* Bpre = Apre + NN*64;            // NN*64
    float* g0   = Bpre + NN*64;            // 2*NB*64
    float* g1   = g0   + 2*NB*64;          // 2*NB*64
    float* acc  = g1   + 2*NB*64;          // 4
    int*   deg  = (int*)(acc + 4);         // NN
    int*   cur  = deg + NN;                // NN
    int*   off  = cur + NN;                // NN+1
    int*   ssrc = off + NN + 1;            // NE
    float* xbuf = Apre;                    // alias (Apre dead after last edge)

    const int* srcv = ei;
    const int* tgtv = ei + NE;
    float* gbuf[2] = {g0, g1};

    k_init<<<128, 256, 0, stream>>>(deg, acc);
    k_pre0<<<NN/32, 256, 0, stream>>>(x, enc_w, enc_b, h, m1w, m1b,
                                      Apre, Bpre, g0, tgtv, deg);
    k_scan<<<1, 256, 0, stream>>>(deg, off);
    k_scat<<<512, 256, 0, stream>>>(srcv, tgtv, off, cur, ssrc);

    for (int l = 0; l < NL; l++) {
        if (l)
            k_preM<<<NN/64, 256, 0, stream>>>(h, m1w + l*128*64, m1b + l*64,
                                              Apre, Bpre,
                                              gbuf[(l+1)&1], gbuf[l&1]);
        k_edge4<<<1024, 256, 0, stream>>>(Apre, Bpre, off, ssrc,
                                          m2w + l*64*64, m2b + l*64, agg);
        k_updateM<<<NN/64, 256, 0, stream>>>(h, agg,
                                             u1w + l*128*64, u1b + l*64,
                                             u2w + l*64*64,  u2b + l*64,
                                             gbuf[l&1]);
    }

    k_dec<<<NN/256, 256, 0, stream>>>(h, dw, db, g0, xbuf, out + 1, acc);
    k_t3<<<NB*32, 256, 0, stream>>>(xbuf, acc, out);
}